// Round 10
// baseline (505.371 us; speedup 1.0000x reference)
//
#include <hip/hip_runtime.h>

// Problem constants: B=2, S=2048, E=1024, H=16, DH=64. All fp32 in/out.
// Pipeline:
//   1) convert q,k,v,Wq,Wk,Wv,Wo fp32->bf16              (1 launch)
//   2) Q/K/V projections, fused bf16 NT-GEMM (z=3 grid)  (1 launch)
//   3) V^T reshape [b][h][d][s] for PV B-fragments       (1 launch)
//   4) fused attention with cross-head logit mixing      (1 launch, k-split x2)
//      S'_g = sum_h M~[g,h] * (Q_h K_h^T), M~ = (I+Wc)*(log2e/8); bc dropped.
//      No max-tracking (bounded logits, exact by shift-invariance).
//      v10: CO-RESIDENCY. v1-v9 invariant: 16-wave convoy, 1 block/CU, 73%
//      no-issue cycles -- latency-bound (per-CU L2 read BW 34 of 135 GB/s).
//      v9's no-max softmax dropped VGPR to 52, so 2 blocks/CU now only needs
//      LDS<=80KB: single-buffered sraw+pbuf (56KB), 2 barriers/k-tile,
//      k-split x2 (grid 512). XCD decode pins (batch,k-half) per XCD ->
//      4MB K/V working set = L2. TLP hides what scheduling never could.
//      No-max merge is exact: O=(O0+O1)/(l0+l1), f32 partials.
//   5) merge k-halves -> Obuf bf16                       (1 launch)
//   6) out = O @ Wo^T + bo, fp32 to d_out                (1 launch)
// Workspace: 0..56MB as before; Op0 @56MB (16MB f32); Ll @72MB (512KB).
// Op1 lives in d_out (dead until final GEMM).

typedef __attribute__((ext_vector_type(8))) short bf16x8_t;   // 8 bf16 (4 VGPRs)
typedef __attribute__((ext_vector_type(4))) short bf16x4_t;   // 4 bf16 (2 VGPRs)
typedef __attribute__((ext_vector_type(4))) float f32x4_t;    // MFMA accumulator

__device__ inline unsigned short f2bf(float f) {
  unsigned u = __builtin_bit_cast(unsigned, f);
  u += 0x7fffu + ((u >> 16) & 1u);          // round-to-nearest-even
  return (unsigned short)(u >> 16);
}

// Volatile asm 16B load (gemm staging): cannot be sunk/elided.
#define GLOAD(dst, ptr) \
  asm volatile("global_load_dwordx4 %0, %1, off" : "=v"(dst) : "v"((const void*)(ptr)))
#define WAITV0() { asm volatile("s_waitcnt vmcnt(0)"); __builtin_amdgcn_sched_barrier(0); }

// Barrier publishing LDS only (no vmcnt drain).
__device__ inline void bar_lds() {
  asm volatile("s_waitcnt lgkmcnt(0)" ::: "memory");
  __builtin_amdgcn_s_barrier();
}

struct ConvArgs {
  const float* src[7];
  unsigned short* dst[7];
  int n[7];
};

__global__ __launch_bounds__(256) void convert_f32_bf16(ConvArgs a) {
  const int which = blockIdx.y;
  const int i = (blockIdx.x * 256 + threadIdx.x) * 8;
  if (i >= a.n[which]) return;
  const float* s = a.src[which] + i;
  f32x4_t x0 = *(const f32x4_t*)(s);
  f32x4_t x1 = *(const f32x4_t*)(s + 4);
  bf16x8_t o;
#pragma unroll
  for (int j = 0; j < 4; j++) o[j] = (short)f2bf(x0[j]);
#pragma unroll
  for (int j = 0; j < 4; j++) o[4 + j] = (short)f2bf(x1[j]);
  *(bf16x8_t*)(a.dst[which] + i) = o;
}

// C[m][n] = sum_k A[m][k] * Bt[n][k] + bias[n].  M,N,K multiples of 128/128/32.
// 256 threads = 4 waves in 2x2; wave tile 64x64 = 4x4 frags of 16x16; BK=32.
// blockIdx.z selects one of up to 3 independent GEMMs (fused QKV launch).
struct GemmArgs {
  const unsigned short* A[3];
  const unsigned short* Bt[3];
  const float* bias[3];
  void* C[3];
  int f32out[3];
};

__global__ __launch_bounds__(256) void gemm_bt(GemmArgs ga, int M, int N, int K)
{
  __shared__ unsigned short As[128 * 32];
  __shared__ unsigned short Bs[128 * 32];
  const int z = blockIdx.z;
  const unsigned short* __restrict__ A  = ga.A[z];
  const unsigned short* __restrict__ Bt = ga.Bt[z];
  const float* __restrict__ bias = ga.bias[z];
  void* __restrict__ C = ga.C[z];
  const int f32out = ga.f32out[z];

  const int t = threadIdx.x;
  const int l = t & 63;
  const int w = t >> 6;
  const int quad = l >> 4, n16 = l & 15;
  const int wm = (w & 1) * 64, wn = (w >> 1) * 64;
  const long m0 = (long)blockIdx.x * 128, n0 = (long)blockIdx.y * 128;

  f32x4_t acc[4][4] = {};

  // staging: thread t covers tile row t/4 (+64 on round 1), cols (t%4)*8..+7
  const unsigned short* gA = A + (m0 + (t >> 2)) * (long)K + (t & 3) * 8;
  const unsigned short* gB = Bt + (n0 + (t >> 2)) * (long)K + (t & 3) * 8;
  const long rowskip = 64l * K;

  bf16x8_t ra0, ra1, rb0, rb1;
  GLOAD(ra0, gA);            GLOAD(ra1, gA + rowskip);
  GLOAD(rb0, gB);            GLOAD(rb1, gB + rowskip);
  WAITV0();                  // tile 0 arrived (no latch crossed)

  for (int kt = 0; kt < K; kt += 32) {
    bar_lds();                             // all waves done reading prior tile
    *(bf16x8_t*)&As[t * 8] = ra0;          // elem (t>>2)*32 + (t&3)*8 == t*8
    *(bf16x8_t*)&As[2048 + t * 8] = ra1;
    *(bf16x8_t*)&Bs[t * 8] = rb0;
    *(bf16x8_t*)&Bs[2048 + t * 8] = rb1;
    bar_lds();                             // staging visible
    const long ktn = (kt + 32 < K) ? kt + 32 : 0;  // clamp (tail loads unused)
    GLOAD(ra0, gA + ktn);      GLOAD(ra1, gA + ktn + rowskip);
    GLOAD(rb0, gB + ktn);      GLOAD(rb1, gB + ktn + rowskip);

    bf16x8_t af[4], bfr[4];
#pragma unroll
    for (int i = 0; i < 4; i++) {
      af[i]  = *(const bf16x8_t*)&As[(wm + i * 16 + n16) * 32 + quad * 8];
      bfr[i] = *(const bf16x8_t*)&Bs[(wn + i * 16 + n16) * 32 + quad * 8];
    }
#pragma unroll
    for (int mi = 0; mi < 4; mi++)
#pragma unroll
      for (int ni = 0; ni < 4; ni++)
        acc[mi][ni] = __builtin_amdgcn_mfma_f32_16x16x32_bf16(af[mi], bfr[ni], acc[mi][ni], 0, 0, 0);
    WAITV0();   // next tile arrived; nothing outstanding crosses the latch
  }

#pragma unroll
  for (int ni = 0; ni < 4; ni++) {
    const long n = n0 + wn + ni * 16 + n16;
    const float bv = bias[n];
#pragma unroll
    for (int mi = 0; mi < 4; mi++) {
#pragma unroll
      for (int r = 0; r < 4; r++) {
        const long m = m0 + wm + mi * 16 + quad * 4 + r;  // D: row=(l>>4)*4+reg, col=l&15
        const float v = acc[mi][ni][r] + bv;
        if (f32out) ((float*)C)[m * N + n] = v;
        else ((unsigned short*)C)[m * N + n] = f2bf(v);
      }
    }
  }
}

// V [b][s][h*64+d] -> VT [b][h][d][s]
__global__ __launch_bounds__(256) void transpose_v(
    const unsigned short* __restrict__ V, unsigned short* __restrict__ VT)
{
  __shared__ unsigned short tile[64][72];   // +8 pad
  const int t = threadIdx.x;
  const int s0 = blockIdx.x * 64, h = blockIdx.y, b = blockIdx.z;
#pragma unroll
  for (int r = 0; r < 2; r++) {
    const int elem = r * 2048 + t * 8;
    const int s = elem >> 6, d = elem & 63;
    *(bf16x8_t*)&tile[s][d] =
        *(const bf16x8_t*)&V[(size_t)(b * 2048 + s0 + s) * 1024 + h * 64 + d];
  }
  __syncthreads();
#pragma unroll
  for (int r = 0; r < 2; r++) {
    const int elem = r * 2048 + t * 8;
    const int d = elem >> 6, sl = elem & 63;
    bf16x8_t o;
#pragma unroll
    for (int j = 0; j < 8; j++) o[j] = (short)tile[sl + j][d];
    *(bf16x8_t*)&VT[((size_t)(b * 16 + h) * 64 + d) * 2048 + s0 + sl] = o;
  }
}

// Fused attention v10. Grid 512 (XCD-decoded, k-split x2). 1024 threads = 16
// waves; 2 blocks/CU co-resident (LDS 56KB, VGPR ~52 <= 64). Wave g: QK^T +
// PV for head g; lane-local logits row (h=n16, q=g) via swapped mix-MFMA;
// p = 2^{S'} directly (no max). Single-buffered sraw/pbuf, 2 barriers/tile:
//   B1: sraw(it) published, pbuf reads (PV it-1) retired
//   mix/exp/pack(it) -> pbuf
//   B2: pbuf published, sraw reads retired
//   PV(it); qk_stage(it+1) -> sraw
// Writes unnormalized f32 partial O + l (exactly summable across k-halves).
__global__ __launch_bounds__(1024, 8) void attention_fused(
    const unsigned short* __restrict__ Qb, const unsigned short* __restrict__ Kb,
    const unsigned short* __restrict__ VT, const float* __restrict__ Wc,
    float* __restrict__ Op0, float* __restrict__ Op1, float* __restrict__ Ll)
{
  __shared__ unsigned short sraw[512 * 36];   // [col=q*32+k][slot 0..31(+4)] 36864 B
  __shared__ unsigned short pbuf[16 * 580];   // [h]{q*36 + k}                18560 B
  __shared__ unsigned short mmat[256];        // M~[g_out][h] row-major       512 B

  const int t = threadIdx.x;
  const int g = t >> 6, l = t & 63;
  const int quad = l >> 4, n16 = l & 15;

  // XCD decode: id&7 = XCD; (batch, k-half) pinned per XCD -> per-XCD K/V
  // working set = 2+2 MB = L2 size.
  const int id = blockIdx.x;
  const int xcd = id & 7;
  const int b = xcd >> 2;
  const int kb = (xcd >> 1) & 1;
  const int qb = (xcd & 1) * 64 + (id >> 3);   // 0..127
  const int q0 = qb * 16;
  const int k0 = kb * 1024;

  // zero sraw once: mix A-operand reads the never-written slot half (h>=16
  // region after XOR) which must be 0, not garbage.
  for (int i = t; i < 512 * 36; i += 1024) sraw[i] = 0;
  if (t < 256) {
    // M~ = (I + Wc) * (log2e / 8): exp2-domain logits
    const float v = ((((t >> 4) == (t & 15)) ? 1.0f : 0.0f) + Wc[t]) * 0.1803368801111204f;
    mmat[t] = f2bf(v);
  }
  __syncthreads();

  // mix B-frag: B[k=h=quad*8+j][n=g_out=n16]; zero for h>=16
  bf16x8_t mfrag;
  if (quad < 2) mfrag = *(const bf16x8_t*)&mmat[n16 * 16 + quad * 8];
  else { bf16x8_t z = {0, 0, 0, 0, 0, 0, 0, 0}; mfrag = z; }
  const int c7 = g >> 2;                     // col>>7 for this wave's mix chunks

  // Q A-frags: A[m=q=n16][k=d]
  bf16x8_t qf[2];
#pragma unroll
  for (int dr = 0; dr < 2; dr++)
    qf[dr] = *(const bf16x8_t*)&Qb[(size_t)(b * 2048 + q0 + n16) * 1024 + g * 64 + dr * 32 + quad * 8];

  const int slot = g ^ (quad << 3);          // sraw h-slot (writer quad == col>>7)
  const unsigned short* kptr = Kb + (size_t)(b * 2048 + k0 + n16) * 1024 + g * 64 + quad * 8;
  const unsigned short* vptr = VT + ((size_t)(b * 16 + g) * 64 + n16) * 2048 + k0 + quad * 8;

  bf16x8_t kf[2][2], vf[4];
  auto load_kf = [&](int kt) {
#pragma unroll
    for (int kc = 0; kc < 2; kc++)
#pragma unroll
      for (int dr = 0; dr < 2; dr++)
        kf[kc][dr] = *(const bf16x8_t*)(kptr + (size_t)(kt + kc * 16) * 1024 + dr * 32);
  };
  auto load_vf = [&](int kt) {
#pragma unroll
    for (int dc = 0; dc < 4; dc++)
      vf[dc] = *(const bf16x8_t*)(vptr + (size_t)dc * 16 * 2048 + kt);
  };
  auto qk_stage = [&]() {
    f32x4_t sf[2] = {};
#pragma unroll
    for (int kc = 0; kc < 2; kc++)
#pragma unroll
      for (int dr = 0; dr < 2; dr++)
        sf[kc] = __builtin_amdgcn_mfma_f32_16x16x32_bf16(qf[dr], kf[kc][dr], sf[kc], 0, 0, 0);
    // D: row=q=quad*4+r, col=key=kc*16+n16 -> sraw[col=q*32+k][slot]
#pragma unroll
    for (int kc = 0; kc < 2; kc++)
#pragma unroll
      for (int r = 0; r < 4; r++)
        sraw[((quad * 4 + r) * 32 + kc * 16 + n16) * 36 + slot] = f2bf(sf[kc][r]);
  };

  // prologue: QK(0) -> sraw
  load_kf(0);
  qk_stage();

  f32x4_t o[4] = {};
  float l_run = 0.0f;

  for (int it = 0; it < 32; ++it) {
    const int kt = it * 32;
    __syncthreads();   // B1: sraw(it) published; pbuf reads (PV it-1) retired

    load_vf(kt);       // consumed at PV after B2

    // ---- head mix (swapped): D[key][g_out] from sraw ----
    f32x4_t mixd[2];
#pragma unroll
    for (int c2 = 0; c2 < 2; c2++) {
      const int c = g * 2 + c2;               // cols [32g+16c2, +16): q=g
      const unsigned short* sp = &sraw[(c * 16 + n16) * 36 + ((quad ^ c7) << 3)];
      bf16x4_t lo = *(const bf16x4_t*)sp;     // A[m=key=n16][k=h=quad*8+j]
      bf16x4_t hi = *(const bf16x4_t*)(sp + 4);
      bf16x8_t aa = {lo[0], lo[1], lo[2], lo[3], hi[0], hi[1], hi[2], hi[3]};
      f32x4_t z = {};
      mixd[c2] = __builtin_amdgcn_mfma_f32_16x16x32_bf16(aa, mfrag, z, 0, 0, 0);
    }
    // lane holds S'[h=n16][q=g][key = c2*16 + quad*4 + r] (log2 domain)

    // ---- p = 2^{S'} directly (bounded logits; no max subtraction) ----
    float p[2][4];
    float lsum = 0.0f;
#pragma unroll
    for (int c2 = 0; c2 < 2; c2++)
#pragma unroll
      for (int r = 0; r < 4; r++) {
        p[c2][r] = exp2f(mixd[c2][r]);
        lsum += p[c2][r];
      }
    l_run += lsum;                            // lane-partial l; reduced at end

    // ---- pack P pairs in-register, write pbuf ----
    const int pbase = n16 * 580 + g * 36 + quad * 4;
#pragma unroll
    for (int c2 = 0; c2 < 2; c2++)
#pragma unroll
      for (int rp = 0; rp < 2; rp++) {
        unsigned pk;
        asm("v_cvt_pk_bf16_f32 %0, %1, %2"
            : "=v"(pk) : "v"(p[c2][2 * rp]), "v"(p[c2][2 * rp + 1]));
        *(unsigned*)&pbuf[pbase + c2 * 16 + 2 * rp] = pk;
      }

    __syncthreads();   // B2: pbuf published; sraw reads retired

    // ---- PV(it) ----
    {
      const unsigned short* pp = &pbuf[g * 580 + n16 * 36 + quad * 8];
      bf16x4_t plo = *(const bf16x4_t*)pp;
      bf16x4_t phi = *(const bf16x4_t*)(pp + 4);
      bf16x8_t pf = {plo[0], plo[1], plo[2], plo[3], phi[0], phi[1], phi[2], phi[3]};
#pragma unroll
      for (int dc = 0; dc < 4; dc++)
        o[dc] = __builtin_amdgcn_mfma_f32_16x16x32_bf16(pf, vf[dc], o[dc], 0, 0, 0);
    }

    // ---- QK(it+1) -> sraw (overwrite OK: all reads retired at B2) ----
    if (it < 31) {
      load_kf(kt + 32);
      qk_stage();
    }
  }

  // ---- epilogue: quad-reduce l, write l + unnormalized f32 partial O ----
  l_run += __shfl_xor(l_run, 16);
  l_run += __shfl_xor(l_run, 32);
  if (quad == 0)
    Ll[((size_t)(kb * 2 + b) * 16 + n16) * 2048 + q0 + g] = l_run;  // (h=n16,q=q0+g)
  float* const ob = kb ? Op1 : Op0;
#pragma unroll
  for (int dc = 0; dc < 4; dc++)
#pragma unroll
    for (int r = 0; r < 4; r++)
      ob[((size_t)(b * 2048 + q0 + quad * 4 + r)) * 1024 + g * 64 + dc * 16 + n16] = o[dc][r];
}

// merge k-halves: O = (O0 + O1) / (l0 + l1)  (exact: both halves unshifted)
__global__ __launch_bounds__(256) void merge_halves(
    const float* __restrict__ Op0, const float* __restrict__ Op1,
    const float* __restrict__ Ll, unsigned short* __restrict__ Obuf)
{
  const int i = blockIdx.x * 256 + threadIdx.x;   // 0..524287, 8 elems each
  const size_t e8 = (size_t)i * 8;
  const int e = (int)(e8 & 1023);
  const int q = (int)((e8 >> 10) & 2047);
  const int b = (int)(e8 >> 21);
  const int h = e >> 6;
  const size_t row = (size_t)b * 2048 + q;
  const size_t mi = ((size_t)b * 16 + h) * 2048 + q;
  const float s = 1.0f / (Ll[mi] + Ll[2 * 16 * 2048 + mi]);
  const float* pa = Op0 + row * 1024 + e;
  const float* pb = Op1 + row * 1024 + e;
  f32x4_t a0 = *(const f32x4_t*)pa, a1 = *(const f32x4_t*)(pa + 4);
  f32x4_t b0 = *(const f32x4_t*)pb, b1 = *(const f32x4_t*)(pb + 4);
  bf16x8_t o8;
#pragma unroll
  for (int j = 0; j < 4; j++) o8[j] = (short)f2bf((a0[j] + b0[j]) * s);
#pragma unroll
  for (int j = 0; j < 4; j++) o8[4 + j] = (short)f2bf((a1[j] + b1[j]) * s);
  *(bf16x8_t*)&Obuf[row * 1024 + e] = o8;
}

extern "C" void kernel_launch(void* const* d_in, const int* in_sizes, int n_in,
                              void* d_out, int out_size, void* d_ws, size_t ws_size,
                              hipStream_t stream) {
  const float* query = (const float*)d_in[0];
  const float* key   = (const float*)d_in[1];
  const float* value = (const float*)d_in[2];
  const float* Wq = (const float*)d_in[3];
  const float* bq = (const float*)d_in[4];
  const float* Wk = (const float*)d_in[5];
  const float* bk = (const float*)d_in[6];
  const float* Wv = (const float*)d_in[7];
  const float* bv = (const float*)d_in[8];
  const float* Wc = (const float*)d_in[9];
  // d_in[10] = bc: constant along softmax axis -> provably no effect on output
  const float* Wo = (const float*)d_in[11];
  const float* bo = (const float*)d_in[12];

  char* ws = (char*)d_ws;
  const size_t MB = 1024 * 1024;
  unsigned short* q_bf  = (unsigned short*)(ws);            // 8MB; later reused as Obuf
  unsigned short* k_bf  = (unsigned short*)(ws + 8 * MB);   // 8MB; later reused as VT
  unsigned short* v_bf  = (unsigned short*)(ws + 16 * MB);  // 8MB
  unsigned short* wq_bf = (unsigned short*)(ws + 24 * MB);  // 2MB
  unsigned short* wk_bf = (unsigned short*)(ws + 26 * MB);  // 2MB
  unsigned short* wv_bf = (unsigned short*)(ws + 28 * MB);  // 2MB
  unsigned short* wo_bf = (unsigned short*)(ws + 30 * MB);  // 2MB
  unsigned short* Qb    = (unsigned short*)(ws + 32 * MB);  // 8MB
  unsigned short* Kb    = (unsigned short*)(ws + 40 * MB);  // 8MB
  unsigned short* Vb    = (unsigned short*)(ws + 48 * MB);  // 8MB
  float* Op0 = (float*)(ws + 56 * MB);                      // 16MB f32 partial (kb=0)
  float* Ll  = (float*)(ws + 72 * MB);                      // 512KB (total 72.5MB)
  float* Op1 = (float*)d_out;                               // 16MB, dead until final GEMM
  unsigned short* VT   = k_bf;   // k_bf dead after K-projection
  unsigned short* Obuf = q_bf;   // q_bf dead after Q-projection

  ConvArgs ca;
  ca.src[0] = query; ca.dst[0] = q_bf;  ca.n[0] = 2 * 2048 * 1024;
  ca.src[1] = key;   ca.dst[1] = k_bf;  ca.n[1] = 2 * 2048 * 1024;
  ca.src[2] = value; ca.dst[2] = v_bf;  ca.n[2] = 2 * 2048 * 1024;
  ca.src[3] = Wq;    ca.dst[3] = wq_bf; ca.n[3] = 1024 * 1024;
  ca.src[4] = Wk;    ca.dst[4] = wk_bf; ca.n[4] = 1024 * 1024;
  ca.src[5] = Wv;    ca.dst[5] = wv_bf; ca.n[5] = 1024 * 1024;
  ca.src[6] = Wo;    ca.dst[6] = wo_bf; ca.n[6] = 1024 * 1024;
  convert_f32_bf16<<<dim3(2048, 7), 256, 0, stream>>>(ca);

  GemmArgs g3;
  g3.A[0] = q_bf; g3.Bt[0] = wq_bf; g3.bias[0] = bq; g3.C[0] = Qb; g3.f32out[0] = 0;
  g3.A[1] = k_bf; g3.Bt[1] = wk_bf; g3.bias[1] = bk; g3.C[1] = Kb; g3.f32out[1] = 0;
  g3.A[2] = v_bf; g3.Bt[2] = wv_bf; g3.bias[2] = bv; g3.C[2] = Vb; g3.f32out[2] = 0;
  gemm_bt<<<dim3(32, 8, 3), 256, 0, stream>>>(g3, 4096, 1024, 1024);

  transpose_v<<<dim3(32, 16, 2), 256, 0, stream>>>(Vb, VT);

  attention_fused<<<dim3(512), 1024, 0, stream>>>(Qb, Kb, VT, Wc, Op0, Op1, Ll);

  merge_halves<<<dim3(2048), 256, 0, stream>>>(Op0, Op1, Ll, Obuf);

  GemmArgs g1;
  g1.A[0] = Obuf; g1.Bt[0] = wo_bf; g1.bias[0] = bo; g1.C[0] = d_out; g1.f32out[0] = 1;
  g1.A[1] = g1.A[0]; g1.Bt[1] = g1.Bt[0]; g1.bias[1] = g1.bias[0]; g1.C[1] = g1.C[0]; g1.f32out[1] = 1;
  g1.A[2] = g1.A[0]; g1.Bt[2] = g1.Bt[0]; g1.bias[2] = g1.bias[0]; g1.C[2] = g1.C[0]; g1.f32out[2] = 1;
  gemm_bt<<<dim3(32, 8, 1), 256, 0, stream>>>(g1, 4096, 1024, 1024);
}

// Round 11
// 442.330 us; speedup vs baseline: 1.1425x; 1.1425x over previous
//
#include <hip/hip_runtime.h>

// Problem constants: B=2, S=2048, E=1024, H=16, DH=64. All fp32 in/out.
// Pipeline:
//   1) convert q,k,v,Wq,Wk,Wv,Wo fp32->bf16              (1 launch)
//   2) Q/K/V projections, fused bf16 NT-GEMM (z=3 grid)  (1 launch)
//   3) V^T reshape [b][h][d][s] for PV B-fragments       (1 launch)
//   4) fused attention with cross-head logit mixing      (1 launch, k-split x2)
//      S'_g = sum_h M~[g,h] * (Q_h K_h^T), M~ = (I+Wc)*(log2e/8); bc dropped.
//      No max-tracking (bounded logits, exact by shift-invariance).
//      v11: 512-THREAD BLOCKS for spill-free co-residency. v3/v10 proved a
//      1024-thread block can't fit 2/CU (64-reg cap -> VGPR 32 + scratch
//      storm: v10 FETCH 37->54MB, WRITE 8->64MB). 8 waves/block, wave w owns
//      heads 2w,2w+1 (2 QK stages, 4 mix chunks, 2 PV accums). 2 blocks/CU
//      = 4 waves/EU -> launch_bounds(512,4) caps at 128 regs: no squeeze.
//      LDS 56KB x2 = 112KB. Same 2-barrier/tile single-buffer loop as v10.
//   5) merge k-halves -> Obuf bf16 (exact: O=(O0+O1)/(l0+l1))  (1 launch)
//   6) out = O @ Wo^T + bo, fp32 to d_out                (1 launch)
// Workspace: 0..56MB as before; Op0 @56MB (16MB f32); Ll @72MB (512KB).
// Op1 lives in d_out (dead until final GEMM).

typedef __attribute__((ext_vector_type(8))) short bf16x8_t;   // 8 bf16 (4 VGPRs)
typedef __attribute__((ext_vector_type(4))) short bf16x4_t;   // 4 bf16 (2 VGPRs)
typedef __attribute__((ext_vector_type(4))) float f32x4_t;    // MFMA accumulator

__device__ inline unsigned short f2bf(float f) {
  unsigned u = __builtin_bit_cast(unsigned, f);
  u += 0x7fffu + ((u >> 16) & 1u);          // round-to-nearest-even
  return (unsigned short)(u >> 16);
}

// Volatile asm 16B load (gemm staging): cannot be sunk/elided.
#define GLOAD(dst, ptr) \
  asm volatile("global_load_dwordx4 %0, %1, off" : "=v"(dst) : "v"((const void*)(ptr)))
#define WAITV0() { asm volatile("s_waitcnt vmcnt(0)"); __builtin_amdgcn_sched_barrier(0); }

// Barrier publishing LDS only (no vmcnt drain).
__device__ inline void bar_lds() {
  asm volatile("s_waitcnt lgkmcnt(0)" ::: "memory");
  __builtin_amdgcn_s_barrier();
}

struct ConvArgs {
  const float* src[7];
  unsigned short* dst[7];
  int n[7];
};

__global__ __launch_bounds__(256) void convert_f32_bf16(ConvArgs a) {
  const int which = blockIdx.y;
  const int i = (blockIdx.x * 256 + threadIdx.x) * 8;
  if (i >= a.n[which]) return;
  const float* s = a.src[which] + i;
  f32x4_t x0 = *(const f32x4_t*)(s);
  f32x4_t x1 = *(const f32x4_t*)(s + 4);
  bf16x8_t o;
#pragma unroll
  for (int j = 0; j < 4; j++) o[j] = (short)f2bf(x0[j]);
#pragma unroll
  for (int j = 0; j < 4; j++) o[4 + j] = (short)f2bf(x1[j]);
  *(bf16x8_t*)(a.dst[which] + i) = o;
}

// C[m][n] = sum_k A[m][k] * Bt[n][k] + bias[n].  M,N,K multiples of 128/128/32.
// 256 threads = 4 waves in 2x2; wave tile 64x64 = 4x4 frags of 16x16; BK=32.
// blockIdx.z selects one of up to 3 independent GEMMs (fused QKV launch).
struct GemmArgs {
  const unsigned short* A[3];
  const unsigned short* Bt[3];
  const float* bias[3];
  void* C[3];
  int f32out[3];
};

__global__ __launch_bounds__(256) void gemm_bt(GemmArgs ga, int M, int N, int K)
{
  __shared__ unsigned short As[128 * 32];
  __shared__ unsigned short Bs[128 * 32];
  const int z = blockIdx.z;
  const unsigned short* __restrict__ A  = ga.A[z];
  const unsigned short* __restrict__ Bt = ga.Bt[z];
  const float* __restrict__ bias = ga.bias[z];
  void* __restrict__ C = ga.C[z];
  const int f32out = ga.f32out[z];

  const int t = threadIdx.x;
  const int l = t & 63;
  const int w = t >> 6;
  const int quad = l >> 4, n16 = l & 15;
  const int wm = (w & 1) * 64, wn = (w >> 1) * 64;
  const long m0 = (long)blockIdx.x * 128, n0 = (long)blockIdx.y * 128;

  f32x4_t acc[4][4] = {};

  // staging: thread t covers tile row t/4 (+64 on round 1), cols (t%4)*8..+7
  const unsigned short* gA = A + (m0 + (t >> 2)) * (long)K + (t & 3) * 8;
  const unsigned short* gB = Bt + (n0 + (t >> 2)) * (long)K + (t & 3) * 8;
  const long rowskip = 64l * K;

  bf16x8_t ra0, ra1, rb0, rb1;
  GLOAD(ra0, gA);            GLOAD(ra1, gA + rowskip);
  GLOAD(rb0, gB);            GLOAD(rb1, gB + rowskip);
  WAITV0();                  // tile 0 arrived (no latch crossed)

  for (int kt = 0; kt < K; kt += 32) {
    bar_lds();                             // all waves done reading prior tile
    *(bf16x8_t*)&As[t * 8] = ra0;          // elem (t>>2)*32 + (t&3)*8 == t*8
    *(bf16x8_t*)&As[2048 + t * 8] = ra1;
    *(bf16x8_t*)&Bs[t * 8] = rb0;
    *(bf16x8_t*)&Bs[2048 + t * 8] = rb1;
    bar_lds();                             // staging visible
    const long ktn = (kt + 32 < K) ? kt + 32 : 0;  // clamp (tail loads unused)
    GLOAD(ra0, gA + ktn);      GLOAD(ra1, gA + ktn + rowskip);
    GLOAD(rb0, gB + ktn);      GLOAD(rb1, gB + ktn + rowskip);

    bf16x8_t af[4], bfr[4];
#pragma unroll
    for (int i = 0; i < 4; i++) {
      af[i]  = *(const bf16x8_t*)&As[(wm + i * 16 + n16) * 32 + quad * 8];
      bfr[i] = *(const bf16x8_t*)&Bs[(wn + i * 16 + n16) * 32 + quad * 8];
    }
#pragma unroll
    for (int mi = 0; mi < 4; mi++)
#pragma unroll
      for (int ni = 0; ni < 4; ni++)
        acc[mi][ni] = __builtin_amdgcn_mfma_f32_16x16x32_bf16(af[mi], bfr[ni], acc[mi][ni], 0, 0, 0);
    WAITV0();   // next tile arrived; nothing outstanding crosses the latch
  }

#pragma unroll
  for (int ni = 0; ni < 4; ni++) {
    const long n = n0 + wn + ni * 16 + n16;
    const float bv = bias[n];
#pragma unroll
    for (int mi = 0; mi < 4; mi++) {
#pragma unroll
      for (int r = 0; r < 4; r++) {
        const long m = m0 + wm + mi * 16 + quad * 4 + r;  // D: row=(l>>4)*4+reg, col=l&15
        const float v = acc[mi][ni][r] + bv;
        if (f32out) ((float*)C)[m * N + n] = v;
        else ((unsigned short*)C)[m * N + n] = f2bf(v);
      }
    }
  }
}

// V [b][s][h*64+d] -> VT [b][h][d][s]
__global__ __launch_bounds__(256) void transpose_v(
    const unsigned short* __restrict__ V, unsigned short* __restrict__ VT)
{
  __shared__ unsigned short tile[64][72];   // +8 pad
  const int t = threadIdx.x;
  const int s0 = blockIdx.x * 64, h = blockIdx.y, b = blockIdx.z;
#pragma unroll
  for (int r = 0; r < 2; r++) {
    const int elem = r * 2048 + t * 8;
    const int s = elem >> 6, d = elem & 63;
    *(bf16x8_t*)&tile[s][d] =
        *(const bf16x8_t*)&V[(size_t)(b * 2048 + s0 + s) * 1024 + h * 64 + d];
  }
  __syncthreads();
#pragma unroll
  for (int r = 0; r < 2; r++) {
    const int elem = r * 2048 + t * 8;
    const int d = elem >> 6, sl = elem & 63;
    bf16x8_t o;
#pragma unroll
    for (int j = 0; j < 8; j++) o[j] = (short)tile[sl + j][d];
    *(bf16x8_t*)&VT[((size_t)(b * 16 + h) * 64 + d) * 2048 + s0 + sl] = o;
  }
}

// Fused attention v11. Grid 512 (XCD-decoded, k-split x2). 512 threads = 8
// waves; wave w owns heads 2w and 2w+1. 2 blocks/CU co-resident (LDS 56KB,
// launch_bounds(512,4) -> 128-reg cap, no squeeze). Lane-local logits row
// (h=n16, q = 2w + c2>>1) via swapped mix-MFMA; p = 2^{S'} (no max).
// Single-buffered sraw/pbuf, 2 barriers/tile:
//   B1: sraw(it) published, pbuf reads (PV it-1) retired
//   mix(4 chunks)/exp/pack(it) -> pbuf
//   B2: pbuf published, sraw reads retired
//   PV(it) both heads; qk_stage(it+1) both heads -> sraw
// Writes unnormalized f32 partial O + l (exactly summable across k-halves).
__global__ __launch_bounds__(512, 4) void attention_fused(
    const unsigned short* __restrict__ Qb, const unsigned short* __restrict__ Kb,
    const unsigned short* __restrict__ VT, const float* __restrict__ Wc,
    float* __restrict__ Op0, float* __restrict__ Op1, float* __restrict__ Ll)
{
  __shared__ unsigned short sraw[512 * 36];   // [col=q*32+k][slot 0..31(+4)] 36864 B
  __shared__ unsigned short pbuf[16 * 580];   // [h]{q*36 + k}                18560 B
  __shared__ unsigned short mmat[256];        // M~[g_out][h] row-major       512 B

  const int t = threadIdx.x;
  const int w = t >> 6, l = t & 63;
  const int quad = l >> 4, n16 = l & 15;
  const int h0 = 2 * w, h1 = 2 * w + 1;

  // XCD decode: id&7 = XCD; (batch, k-half) pinned per XCD -> per-XCD K/V
  // working set = 2+2 MB = L2 size.
  const int id = blockIdx.x;
  const int xcd = id & 7;
  const int b = xcd >> 2;
  const int kb = (xcd >> 1) & 1;
  const int qb = (xcd & 1) * 64 + (id >> 3);   // 0..127
  const int q0 = qb * 16;
  const int k0 = kb * 1024;

  // zero sraw once: mix A-operand reads the never-written slot half (after
  // the XOR swizzle) which must be 0, not garbage.
  for (int i = t; i < 512 * 36; i += 512) sraw[i] = 0;
  if (t < 256) {
    // M~ = (I + Wc) * (log2e / 8): exp2-domain logits
    const float v = ((((t >> 4) == (t & 15)) ? 1.0f : 0.0f) + Wc[t]) * 0.1803368801111204f;
    mmat[t] = f2bf(v);
  }
  __syncthreads();

  // mix B-frag: B[k=h=quad*8+j][n=g_out=n16]; zero for h>=16
  bf16x8_t mfrag;
  if (quad < 2) mfrag = *(const bf16x8_t*)&mmat[n16 * 16 + quad * 8];
  else { bf16x8_t z = {0, 0, 0, 0, 0, 0, 0, 0}; mfrag = z; }
  const int c7 = w >> 1;   // col>>7 for ALL 4 of this wave's mix chunks (c=4w+c2)

  // Q A-frags for both heads: A[m=q=n16][k=d]
  bf16x8_t qf0[2], qf1[2];
#pragma unroll
  for (int dr = 0; dr < 2; dr++) {
    qf0[dr] = *(const bf16x8_t*)&Qb[(size_t)(b * 2048 + q0 + n16) * 1024 + h0 * 64 + dr * 32 + quad * 8];
    qf1[dr] = *(const bf16x8_t*)&Qb[(size_t)(b * 2048 + q0 + n16) * 1024 + h1 * 64 + dr * 32 + quad * 8];
  }

  const int slot0 = h0 ^ (quad << 3);        // sraw h-slot (writer quad == col>>7)
  const int slot1 = h1 ^ (quad << 3);
  const unsigned short* kptr0 = Kb + (size_t)(b * 2048 + k0 + n16) * 1024 + h0 * 64 + quad * 8;
  const unsigned short* kptr1 = Kb + (size_t)(b * 2048 + k0 + n16) * 1024 + h1 * 64 + quad * 8;
  const unsigned short* vptr0 = VT + ((size_t)(b * 16 + h0) * 64 + n16) * 2048 + k0 + quad * 8;
  const unsigned short* vptr1 = VT + ((size_t)(b * 16 + h1) * 64 + n16) * 2048 + k0 + quad * 8;

  // QK for one head: load K frags, 4 MFMA, scatter to sraw slots.
  auto qk_head = [&](const unsigned short* kp, const bf16x8_t* qf, int slot, int kt) {
    bf16x8_t kf[2][2];
#pragma unroll
    for (int kc = 0; kc < 2; kc++)
#pragma unroll
      for (int dr = 0; dr < 2; dr++)
        kf[kc][dr] = *(const bf16x8_t*)(kp + (size_t)(kt + kc * 16) * 1024 + dr * 32);
    f32x4_t sf[2] = {};
#pragma unroll
    for (int kc = 0; kc < 2; kc++)
#pragma unroll
      for (int dr = 0; dr < 2; dr++)
        sf[kc] = __builtin_amdgcn_mfma_f32_16x16x32_bf16(qf[dr], kf[kc][dr], sf[kc], 0, 0, 0);
    // D: row=q=quad*4+r, col=key=kc*16+n16 -> sraw[col=q*32+k][slot]
#pragma unroll
    for (int kc = 0; kc < 2; kc++)
#pragma unroll
      for (int r = 0; r < 4; r++)
        sraw[((quad * 4 + r) * 32 + kc * 16 + n16) * 36 + slot] = f2bf(sf[kc][r]);
  };

  // prologue: QK(0) for both heads -> sraw
  qk_head(kptr0, qf0, slot0, 0);
  qk_head(kptr1, qf1, slot1, 0);

  f32x4_t o0[4] = {}, o1[4] = {};
  float l_run0 = 0.0f, l_run1 = 0.0f;

  for (int it = 0; it < 32; ++it) {
    const int kt = it * 32;
    __syncthreads();   // B1: sraw(it) published; pbuf reads (PV it-1) retired

    // ---- head mix (swapped): 4 chunks, cols [64w, 64w+64) = q-rows 2w,2w+1 ----
    f32x4_t mixd[4];
#pragma unroll
    for (int c2 = 0; c2 < 4; c2++) {
      const int c = 4 * w + c2;
      const unsigned short* sp = &sraw[(c * 16 + n16) * 36 + ((quad ^ c7) << 3)];
      bf16x4_t lo = *(const bf16x4_t*)sp;     // A[m=key=n16][k=h=quad*8+j]
      bf16x4_t hi = *(const bf16x4_t*)(sp + 4);
      bf16x8_t aa = {lo[0], lo[1], lo[2], lo[3], hi[0], hi[1], hi[2], hi[3]};
      f32x4_t z = {};
      mixd[c2] = __builtin_amdgcn_mfma_f32_16x16x32_bf16(aa, mfrag, z, 0, 0, 0);
    }
    // lane holds S'[h=n16][q=2w+(c2>>1)][key=(c2&1)*16+quad*4+r] (log2 domain)

    // ---- p = 2^{S'} directly (bounded logits; no max subtraction) ----
    float p[4][4];
#pragma unroll
    for (int c2 = 0; c2 < 4; c2++) {
      float ls = 0.0f;
#pragma unroll
      for (int r = 0; r < 4; r++) {
        p[c2][r] = exp2f(mixd[c2][r]);
        ls += p[c2][r];
      }
      if (c2 < 2) l_run0 += ls; else l_run1 += ls;   // lane-partial l per q-row
    }

    // ---- pack P pairs in-register, write pbuf ----
#pragma unroll
    for (int c2 = 0; c2 < 4; c2++) {
      const int pb_ = n16 * 580 + (2 * w + (c2 >> 1)) * 36 + (c2 & 1) * 16 + quad * 4;
#pragma unroll
      for (int rp = 0; rp < 2; rp++) {
        unsigned pk;
        asm("v_cvt_pk_bf16_f32 %0, %1, %2"
            : "=v"(pk) : "v"(p[c2][2 * rp]), "v"(p[c2][2 * rp + 1]));
        *(unsigned*)&pbuf[pb_ + 2 * rp] = pk;
      }
    }

    __syncthreads();   // B2: pbuf published; sraw reads retired

    // ---- PV(it) for both heads ----
    {
      const unsigned short* pp = &pbuf[h0 * 580 + n16 * 36 + quad * 8];
      bf16x4_t plo = *(const bf16x4_t*)pp;
      bf16x4_t phi = *(const bf16x4_t*)(pp + 4);
      bf16x8_t pf = {plo[0], plo[1], plo[2], plo[3], phi[0], phi[1], phi[2], phi[3]};
#pragma unroll
      for (int dc = 0; dc < 4; dc++) {
        bf16x8_t vfd = *(const bf16x8_t*)(vptr0 + (size_t)dc * 16 * 2048 + kt);
        o0[dc] = __builtin_amdgcn_mfma_f32_16x16x32_bf16(pf, vfd, o0[dc], 0, 0, 0);
      }
    }
    {
      const unsigned short* pp = &pbuf[h1 * 580 + n16 * 36 + quad * 8];
      bf16x4_t plo = *(const bf16x4_t*)pp;
      bf16x4_t phi = *(const bf16x4_t*)(pp + 4);
      bf16x8_t pf = {plo[0], plo[1], plo[2], plo[3], phi[0], phi[1], phi[2], phi[3]};
#pragma unroll
      for (int dc = 0; dc < 4; dc++) {
        bf16x8_t vfd = *(const bf16x8_t*)(vptr1 + (size_t)dc * 16 * 2048 + kt);
        o1[dc] = __builtin_amdgcn_mfma_f32_16x16x32_bf16(pf, vfd, o1[dc], 0, 0, 0);
      }
    }

    // ---- QK(it+1) -> sraw (overwrite OK: all reads retired at B2) ----
    if (it < 31) {
      qk_head(kptr0, qf0, slot0, kt + 32);
      qk_head(kptr1, qf1, slot1, kt + 32);
    }
  }

  // ---- epilogue: quad-reduce l, write l + unnormalized f32 partial O ----
  l_run0 += __shfl_xor(l_run0, 16);
  l_run0 += __shfl_xor(l_run0, 32);
  l_run1 += __shfl_xor(l_run1, 16);
  l_run1 += __shfl_xor(l_run1, 32);
  if (quad == 0) {
    const size_t lbase = ((size_t)(kb * 2 + b) * 16 + n16) * 2048 + q0;
    Ll[lbase + 2 * w]     = l_run0;          // row (h=n16, q=q0+2w)
    Ll[lbase + 2 * w + 1] = l_run1;          // row (h=n16, q=q0+2w+1)
  }
  float* const ob = kb ? Op1 : Op0;
#pragma unroll
  for (int dc = 0; dc < 4; dc++)
#pragma unroll
    for (int r = 0; r < 4; r++) {
      const size_t row = (size_t)(b * 2048 + q0 + quad * 4 + r) * 1024;
      ob[row + h0 * 64 + dc * 16 + n16] = o0[dc][r];
      ob[row + h1 * 64 + dc * 16 + n16] = o1[dc][r];
    }
}

// merge k-halves: O = (O0 + O1) / (l0 + l1)  (exact: both halves unshifted)
__global__ __launch_bounds__(256) void merge_halves(
    const float* __restrict__ Op0, const float* __restrict__ Op1,
    const float* __restrict__ Ll, unsigned short* __restrict__ Obuf)
{
  const int i = blockIdx.x * 256 + threadIdx.x;   // 0..524287, 8 elems each
  const size_t e8 = (size_t)i * 8;
  const int e = (int)(e8 & 1023);
  const int q = (int)((e8 >> 10) & 2047);
  const int b = (int)(e8 >> 21);
  const int h = e >> 6;
  const size_t row = (size_t)b * 2048 + q;
  const size_t mi = ((size_t)b * 16 + h) * 2048 + q;
  const float s = 1.0f / (Ll[mi] + Ll[2 * 16 * 2048 + mi]);
  const float* pa = Op0 + row * 1024 + e;
  const float* pb = Op1 + row * 1024 + e;
  f32x4_t a0 = *(const f32x4_t*)pa, a1 = *(const f32x4_t*)(pa + 4);
  f32x4_t b0 = *(const f32x4_t*)pb, b1 = *(const f32x4_t*)(pb + 4);
  bf16x8_t o8;
#pragma unroll
  for (int j = 0; j < 4; j++) o8[j] = (short)f2bf((a0[j] + b0[j]) * s);
#pragma unroll
  for (int j = 0; j < 4; j++) o8[4 + j] = (short)f2bf((a1[j] + b1[j]) * s);
  *(bf16x8_t*)&Obuf[row * 1024 + e] = o8;
}

extern "C" void kernel_launch(void* const* d_in, const int* in_sizes, int n_in,
                              void* d_out, int out_size, void* d_ws, size_t ws_size,
                              hipStream_t stream) {
  const float* query = (const float*)d_in[0];
  const float* key   = (const float*)d_in[1];
  const float* value = (const float*)d_in[2];
  const float* Wq = (const float*)d_in[3];
  const float* bq = (const float*)d_in[4];
  const float* Wk = (const float*)d_in[5];
  const float* bk = (const float*)d_in[6];
  const float* Wv = (const float*)d_in[7];
  const float* bv = (const float*)d_in[8];
  const float* Wc = (const float*)d_in[9];
  // d_in[10] = bc: constant along softmax axis -> provably no effect on output
  const float* Wo = (const float*)d_in[11];
  const float* bo = (const float*)d_in[12];

  char* ws = (char*)d_ws;
  const size_t MB = 1024 * 1024;
  unsigned short* q_bf  = (unsigned short*)(ws);            // 8MB; later reused as Obuf
  unsigned short* k_bf  = (unsigned short*)(ws + 8 * MB);   // 8MB; later reused as VT
  unsigned short* v_bf  = (unsigned short*)(ws + 16 * MB);  // 8MB
  unsigned short* wq_bf = (unsigned short*)(ws + 24 * MB);  // 2MB
  unsigned short* wk_bf = (unsigned short*)(ws + 26 * MB);  // 2MB
  unsigned short* wv_bf = (unsigned short*)(ws + 28 * MB);  // 2MB
  unsigned short* wo_bf = (unsigned short*)(ws + 30 * MB);  // 2MB
  unsigned short* Qb    = (unsigned short*)(ws + 32 * MB);  // 8MB
  unsigned short* Kb    = (unsigned short*)(ws + 40 * MB);  // 8MB
  unsigned short* Vb    = (unsigned short*)(ws + 48 * MB);  // 8MB
  float* Op0 = (float*)(ws + 56 * MB);                      // 16MB f32 partial (kb=0)
  float* Ll  = (float*)(ws + 72 * MB);                      // 512KB (total 72.5MB)
  float* Op1 = (float*)d_out;                               // 16MB, dead until final GEMM
  unsigned short* VT   = k_bf;   // k_bf dead after K-projection
  unsigned short* Obuf = q_bf;   // q_bf dead after Q-projection

  ConvArgs ca;
  ca.src[0] = query; ca.dst[0] = q_bf;  ca.n[0] = 2 * 2048 * 1024;
  ca.src[1] = key;   ca.dst[1] = k_bf;  ca.n[1] = 2 * 2048 * 1024;
  ca.src[2] = value; ca.dst[2] = v_bf;  ca.n[2] = 2 * 2048 * 1024;
  ca.src[3] = Wq;    ca.dst[3] = wq_bf; ca.n[3] = 1024 * 1024;
  ca.src[4] = Wk;    ca.dst[4] = wk_bf; ca.n[4] = 1024 * 1024;
  ca.src[5] = Wv;    ca.dst[5] = wv_bf; ca.n[5] = 1024 * 1024;
  ca.src[6] = Wo;    ca.dst[6] = wo_bf; ca.n[6] = 1024 * 1024;
  convert_f32_bf16<<<dim3(2048, 7), 256, 0, stream>>>(ca);

  GemmArgs g3;
  g3.A[0] = q_bf; g3.Bt[0] = wq_bf; g3.bias[0] = bq; g3.C[0] = Qb; g3.f32out[0] = 0;
  g3.A[1] = k_bf; g3.Bt[1] = wk_bf; g3.bias[1] = bk; g3.C[1] = Kb; g3.f32out[1] = 0;
  g3.A[2] = v_bf; g3.Bt[2] = wv_bf; g3.bias[2] = bv; g3.C[2] = Vb; g3.f32out[2] = 0;
  gemm_bt<<<dim3(32, 8, 3), 256, 0, stream>>>(g3, 4096, 1024, 1024);

  transpose_v<<<dim3(32, 16, 2), 256, 0, stream>>>(Vb, VT);

  attention_fused<<<dim3(512), 512, 0, stream>>>(Qb, Kb, VT, Wc, Op0, Op1, Ll);

  merge_halves<<<dim3(2048), 256, 0, stream>>>(Op0, Op1, Ll, Obuf);

  GemmArgs g1;
  g1.A[0] = Obuf; g1.Bt[0] = wo_bf; g1.bias[0] = bo; g1.C[0] = d_out; g1.f32out[0] = 1;
  g1.A[1] = g1.A[0]; g1.Bt[1] = g1.Bt[0]; g1.bias[1] = g1.bias[0]; g1.C[1] = g1.C[0]; g1.f32out[1] = 1;
  g1.A[2] = g1.A[0]; g1.Bt[2] = g1.Bt[0]; g1.bias[2] = g1.bias[0]; g1.C[2] = g1.C[0]; g1.f32out[2] = 1;
  gemm_bt<<<dim3(32, 8, 1), 256, 0, stream>>>(g1, 4096, 1024, 1024);
}

// Round 12
// 437.784 us; speedup vs baseline: 1.1544x; 1.0104x over previous
//
#include <hip/hip_runtime.h>

// Problem constants: B=2, S=2048, E=1024, H=16, DH=64. All fp32 in/out.
// Pipeline:
//   1) convert q,k,v,Wq,Wk,Wv,Wo fp32->bf16              (1 launch)
//   2) Q/K/V projections, fused bf16 NT-GEMM (z=3 grid)  (1 launch)
//   3) V^T reshape [b][h][d][s] for PV B-fragments       (1 launch)
//   4) fused attention with cross-head logit mixing      (1 launch)
//      S'_g = sum_h M~[g,h] * (Q_h K_h^T), M~ = (I+Wc)*(log2e/8); bc dropped.
//      No max-tracking (bounded logits, exact by shift-invariance).
//      v12: Tk=64 (32 intervals, was 64). v1-v11 law: ~9.2K cycles per
//      head-iter unit, invariant to scheduling/occupancy/buffering -- all
//      latencies serially exposed in a phase-locked convoy. v12 doubles
//      work per barrier interval AND batches all 16 global loads (K(it+1),
//      V(it)) right after B1: __syncthreads' vmcnt drain at B2 means they
//      are covered by the mix/exp/pack region (~700cy) and consumed after
//      B2. Tests whether interval amortization + intra-wave load batching
//      breaks the linear unit-cost law.
//   5) out = O @ Wo^T + bo, fp32 to d_out                (1 launch)
// Workspace layout (56 MB total, reuse: O overlays q_bf, VT overlays k_bf).

typedef __attribute__((ext_vector_type(8))) short bf16x8_t;   // 8 bf16 (4 VGPRs)
typedef __attribute__((ext_vector_type(4))) short bf16x4_t;   // 4 bf16 (2 VGPRs)
typedef __attribute__((ext_vector_type(4))) float f32x4_t;    // MFMA accumulator

__device__ inline unsigned short f2bf(float f) {
  unsigned u = __builtin_bit_cast(unsigned, f);
  u += 0x7fffu + ((u >> 16) & 1u);          // round-to-nearest-even
  return (unsigned short)(u >> 16);
}

// Volatile asm 16B load (gemm staging): cannot be sunk/elided.
#define GLOAD(dst, ptr) \
  asm volatile("global_load_dwordx4 %0, %1, off" : "=v"(dst) : "v"((const void*)(ptr)))
#define WAITV0() { asm volatile("s_waitcnt vmcnt(0)"); __builtin_amdgcn_sched_barrier(0); }

// Barrier publishing LDS only (no vmcnt drain).
__device__ inline void bar_lds() {
  asm volatile("s_waitcnt lgkmcnt(0)" ::: "memory");
  __builtin_amdgcn_s_barrier();
}

struct ConvArgs {
  const float* src[7];
  unsigned short* dst[7];
  int n[7];
};

__global__ __launch_bounds__(256) void convert_f32_bf16(ConvArgs a) {
  const int which = blockIdx.y;
  const int i = (blockIdx.x * 256 + threadIdx.x) * 8;
  if (i >= a.n[which]) return;
  const float* s = a.src[which] + i;
  f32x4_t x0 = *(const f32x4_t*)(s);
  f32x4_t x1 = *(const f32x4_t*)(s + 4);
  bf16x8_t o;
#pragma unroll
  for (int j = 0; j < 4; j++) o[j] = (short)f2bf(x0[j]);
#pragma unroll
  for (int j = 0; j < 4; j++) o[4 + j] = (short)f2bf(x1[j]);
  *(bf16x8_t*)(a.dst[which] + i) = o;
}

// C[m][n] = sum_k A[m][k] * Bt[n][k] + bias[n].  M,N,K multiples of 128/128/32.
// 256 threads = 4 waves in 2x2; wave tile 64x64 = 4x4 frags of 16x16; BK=32.
// blockIdx.z selects one of up to 3 independent GEMMs (fused QKV launch).
struct GemmArgs {
  const unsigned short* A[3];
  const unsigned short* Bt[3];
  const float* bias[3];
  void* C[3];
  int f32out[3];
};

__global__ __launch_bounds__(256) void gemm_bt(GemmArgs ga, int M, int N, int K)
{
  __shared__ unsigned short As[128 * 32];
  __shared__ unsigned short Bs[128 * 32];
  const int z = blockIdx.z;
  const unsigned short* __restrict__ A  = ga.A[z];
  const unsigned short* __restrict__ Bt = ga.Bt[z];
  const float* __restrict__ bias = ga.bias[z];
  void* __restrict__ C = ga.C[z];
  const int f32out = ga.f32out[z];

  const int t = threadIdx.x;
  const int l = t & 63;
  const int w = t >> 6;
  const int quad = l >> 4, n16 = l & 15;
  const int wm = (w & 1) * 64, wn = (w >> 1) * 64;
  const long m0 = (long)blockIdx.x * 128, n0 = (long)blockIdx.y * 128;

  f32x4_t acc[4][4] = {};

  // staging: thread t covers tile row t/4 (+64 on round 1), cols (t%4)*8..+7
  const unsigned short* gA = A + (m0 + (t >> 2)) * (long)K + (t & 3) * 8;
  const unsigned short* gB = Bt + (n0 + (t >> 2)) * (long)K + (t & 3) * 8;
  const long rowskip = 64l * K;

  bf16x8_t ra0, ra1, rb0, rb1;
  GLOAD(ra0, gA);            GLOAD(ra1, gA + rowskip);
  GLOAD(rb0, gB);            GLOAD(rb1, gB + rowskip);
  WAITV0();                  // tile 0 arrived (no latch crossed)

  for (int kt = 0; kt < K; kt += 32) {
    bar_lds();                             // all waves done reading prior tile
    *(bf16x8_t*)&As[t * 8] = ra0;          // elem (t>>2)*32 + (t&3)*8 == t*8
    *(bf16x8_t*)&As[2048 + t * 8] = ra1;
    *(bf16x8_t*)&Bs[t * 8] = rb0;
    *(bf16x8_t*)&Bs[2048 + t * 8] = rb1;
    bar_lds();                             // staging visible
    const long ktn = (kt + 32 < K) ? kt + 32 : 0;  // clamp (tail loads unused)
    GLOAD(ra0, gA + ktn);      GLOAD(ra1, gA + ktn + rowskip);
    GLOAD(rb0, gB + ktn);      GLOAD(rb1, gB + ktn + rowskip);

    bf16x8_t af[4], bfr[4];
#pragma unroll
    for (int i = 0; i < 4; i++) {
      af[i]  = *(const bf16x8_t*)&As[(wm + i * 16 + n16) * 32 + quad * 8];
      bfr[i] = *(const bf16x8_t*)&Bs[(wn + i * 16 + n16) * 32 + quad * 8];
    }
#pragma unroll
    for (int mi = 0; mi < 4; mi++)
#pragma unroll
      for (int ni = 0; ni < 4; ni++)
        acc[mi][ni] = __builtin_amdgcn_mfma_f32_16x16x32_bf16(af[mi], bfr[ni], acc[mi][ni], 0, 0, 0);
    WAITV0();   // next tile arrived; nothing outstanding crosses the latch
  }

#pragma unroll
  for (int ni = 0; ni < 4; ni++) {
    const long n = n0 + wn + ni * 16 + n16;
    const float bv = bias[n];
#pragma unroll
    for (int mi = 0; mi < 4; mi++) {
#pragma unroll
      for (int r = 0; r < 4; r++) {
        const long m = m0 + wm + mi * 16 + quad * 4 + r;  // D: row=(l>>4)*4+reg, col=l&15
        const float v = acc[mi][ni][r] + bv;
        if (f32out) ((float*)C)[m * N + n] = v;
        else ((unsigned short*)C)[m * N + n] = f2bf(v);
      }
    }
  }
}

// V [b][s][h*64+d] -> VT [b][h][d][s]
__global__ __launch_bounds__(256) void transpose_v(
    const unsigned short* __restrict__ V, unsigned short* __restrict__ VT)
{
  __shared__ unsigned short tile[64][72];   // +8 pad
  const int t = threadIdx.x;
  const int s0 = blockIdx.x * 64, h = blockIdx.y, b = blockIdx.z;
#pragma unroll
  for (int r = 0; r < 2; r++) {
    const int elem = r * 2048 + t * 8;
    const int s = elem >> 6, d = elem & 63;
    *(bf16x8_t*)&tile[s][d] =
        *(const bf16x8_t*)&V[(size_t)(b * 2048 + s0 + s) * 1024 + h * 64 + d];
  }
  __syncthreads();
#pragma unroll
  for (int r = 0; r < 2; r++) {
    const int elem = r * 2048 + t * 8;
    const int d = elem >> 6, sl = elem & 63;
    bf16x8_t o;
#pragma unroll
    for (int j = 0; j < 8; j++) o[j] = (short)tile[sl + j][d];
    *(bf16x8_t*)&VT[((size_t)(b * 16 + h) * 64 + d) * 2048 + s0 + sl] = o;
  }
}

// Fused attention v12. Grid 256 (1-D, XCD-decoded). 1024 threads = 16 waves,
// wave g: head g. Tk=64 keys per interval, 32 intervals. Lane-local logits
// row (h=n16, q=g) via swapped mix-MFMA; p = 2^{S'} (no max). Single-buffered
// sraw/pbuf, 2 barriers/interval:
//   B1: sraw(it) published; pbuf reads (PV it-1... same-interval) retired
//   [issue 8 V(it) + 8 K(it+1) loads -- drained by B2's vmcnt, covered by mix]
//   mix(4 chunks)/exp(16)/pack -> pbuf
//   B2: pbuf published; sraw reads retired; global loads drained
//   PV(it) (pbuf + vf); QK(it+1) (kf) -> sraw
// sraw slot swizzle (Tk=64): writer f=col>>8=quad (unchanged); reader
// c7=g>>2 (unchanged) -- verified bijective per col, h>=16 reads hit
// never-written zeroed slots.
__global__ __launch_bounds__(1024, 4) void attention_fused(
    const unsigned short* __restrict__ Qb, const unsigned short* __restrict__ Kb,
    const unsigned short* __restrict__ VT, const float* __restrict__ Wc,
    unsigned short* __restrict__ Obuf)
{
  __shared__ unsigned short sraw[1024 * 36];  // [col=q*64+k][slot 0..31(+4)] 73728 B
  __shared__ unsigned short pbuf[16 * 1092];  // [h]{q*68 + k}, pad stride     34944 B
  __shared__ float lbuf[16 * 17];             // [h][q] stride 17              1088 B
  __shared__ unsigned short mmat[256];        // M~[g_out][h] row-major        512 B

  const int t = threadIdx.x;
  const int g = t >> 6, l = t & 63;
  const int quad = l >> 4, n16 = l & 15;

  // XCD decode: id&7 = XCD; batch pinned to an XCD half
  const int id = blockIdx.x;
  const int xcd = id & 7;
  const int b = xcd >> 2;
  const int qb = (xcd & 3) * 32 + (id >> 3);
  const int q0 = qb * 16;

  // zero sraw once: mix A-operand reads the never-written slot half (after
  // the XOR swizzle) which must be 0, not garbage.
  for (int i = t; i < 1024 * 36; i += 1024) sraw[i] = 0;
  if (t < 256) {
    // M~ = (I + Wc) * (log2e / 8): exp2-domain logits
    const float v = ((((t >> 4) == (t & 15)) ? 1.0f : 0.0f) + Wc[t]) * 0.1803368801111204f;
    mmat[t] = f2bf(v);
  }
  __syncthreads();

  // mix B-frag: B[k=h=quad*8+j][n=g_out=n16]; zero for h>=16
  bf16x8_t mfrag;
  if (quad < 2) mfrag = *(const bf16x8_t*)&mmat[n16 * 16 + quad * 8];
  else { bf16x8_t z = {0, 0, 0, 0, 0, 0, 0, 0}; mfrag = z; }
  const int c7 = g >> 2;                     // (col>>8) for this wave's 4 mix chunks

  // Q A-frags: A[m=q=n16][k=d]
  bf16x8_t qf[2];
#pragma unroll
  for (int dr = 0; dr < 2; dr++)
    qf[dr] = *(const bf16x8_t*)&Qb[(size_t)(b * 2048 + q0 + n16) * 1024 + g * 64 + dr * 32 + quad * 8];

  const int slot = g ^ (quad << 3);          // sraw h-slot (writer quad == col>>8)
  const unsigned short* kptr = Kb + (size_t)(b * 2048 + n16) * 1024 + g * 64 + quad * 8;
  const unsigned short* vptr = VT + ((size_t)(b * 16 + g) * 64 + n16) * 2048 + quad * 8;

  bf16x8_t kf[4][2], vf[4][2];
  auto load_kf = [&](int kt) {               // 8 loads: K rows kt..kt+63
#pragma unroll
    for (int kc = 0; kc < 4; kc++)
#pragma unroll
      for (int dr = 0; dr < 2; dr++)
        kf[kc][dr] = *(const bf16x8_t*)(kptr + (size_t)(kt + kc * 16) * 1024 + dr * 32);
  };
  auto load_vf = [&](int kt) {               // 8 loads: V cols kt..kt+63
#pragma unroll
    for (int dc = 0; dc < 4; dc++)
#pragma unroll
      for (int kc2 = 0; kc2 < 2; kc2++)
        vf[dc][kc2] = *(const bf16x8_t*)(vptr + (size_t)dc * 16 * 2048 + kt + kc2 * 32);
  };
  auto qk_stage = [&]() {                    // 8 MFMA + 16 b16 scatter writes
    f32x4_t sf[4] = {};
#pragma unroll
    for (int kc = 0; kc < 4; kc++)
#pragma unroll
      for (int dr = 0; dr < 2; dr++)
        sf[kc] = __builtin_amdgcn_mfma_f32_16x16x32_bf16(qf[dr], kf[kc][dr], sf[kc], 0, 0, 0);
    // D: row=q=quad*4+r, col=key=kc*16+n16 -> sraw[col=q*64+key][slot]
#pragma unroll
    for (int kc = 0; kc < 4; kc++)
#pragma unroll
      for (int r = 0; r < 4; r++)
        sraw[((quad * 4 + r) * 64 + kc * 16 + n16) * 36 + slot] = f2bf(sf[kc][r]);
  };

  // prologue: QK(0) -> sraw
  load_kf(0);
  qk_stage();

  f32x4_t o[4] = {};
  float l_run = 0.0f;

  for (int it = 0; it < 32; ++it) {
    const int kt = it * 64;
    __syncthreads();   // B1: sraw(it) published; prior pbuf/sraw-write hazards retired

    // ---- batch-issue ALL global loads for this interval (16 dwordx4).
    // Drained by B2's vmcnt(0); latency covered by mix/exp/pack below. ----
    load_vf(kt);                       // consumed at PV after B2
    if (it < 31) load_kf(kt + 64);     // consumed at QK(it+1) after B2

    // ---- head mix (swapped): 4 chunks, cols [64g, 64g+64) = q-row g ----
    f32x4_t mixd[4];
#pragma unroll
    for (int c2 = 0; c2 < 4; c2++) {
      const int c = g * 4 + c2;
      const unsigned short* sp = &sraw[(c * 16 + n16) * 36 + ((quad ^ c7) << 3)];
      bf16x4_t lo = *(const bf16x4_t*)sp;     // A[m=key=n16][k=h=quad*8+j]
      bf16x4_t hi = *(const bf16x4_t*)(sp + 4);
      bf16x8_t aa = {lo[0], lo[1], lo[2], lo[3], hi[0], hi[1], hi[2], hi[3]};
      f32x4_t z = {};
      mixd[c2] = __builtin_amdgcn_mfma_f32_16x16x32_bf16(aa, mfrag, z, 0, 0, 0);
    }
    // lane holds S'[h=n16][q=g][key = c2*16 + quad*4 + r] (log2 domain)

    // ---- p = 2^{S'} directly (bounded logits; no max subtraction) ----
    float p[4][4];
    float lsum = 0.0f;
#pragma unroll
    for (int c2 = 0; c2 < 4; c2++)
#pragma unroll
      for (int r = 0; r < 4; r++) {
        p[c2][r] = exp2f(mixd[c2][r]);
        lsum += p[c2][r];
      }
    l_run += lsum;                            // lane-partial l; reduced at end

    // ---- pack P pairs in-register, write pbuf ----
#pragma unroll
    for (int c2 = 0; c2 < 4; c2++) {
      const int pb_ = n16 * 1092 + g * 68 + c2 * 16 + quad * 4;
      unsigned pk0, pk1;
      asm("v_cvt_pk_bf16_f32 %0, %1, %2" : "=v"(pk0) : "v"(p[c2][0]), "v"(p[c2][1]));
      asm("v_cvt_pk_bf16_f32 %0, %1, %2" : "=v"(pk1) : "v"(p[c2][2]), "v"(p[c2][3]));
      *(unsigned*)&pbuf[pb_] = pk0;
      *(unsigned*)&pbuf[pb_ + 2] = pk1;
    }

    __syncthreads();   // B2: pbuf published; sraw reads retired; loads drained

    // ---- PV(it): P[q16 x k64] @ V[k64 x d64], 8 MFMA ----
#pragma unroll
    for (int kc2 = 0; kc2 < 2; kc2++) {
      const unsigned short* pp = &pbuf[g * 1092 + n16 * 68 + kc2 * 32 + quad * 8];
      bf16x4_t plo = *(const bf16x4_t*)pp;
      bf16x4_t phi = *(const bf16x4_t*)(pp + 4);
      bf16x8_t pf = {plo[0], plo[1], plo[2], plo[3], phi[0], phi[1], phi[2], phi[3]};
#pragma unroll
      for (int dc = 0; dc < 4; dc++)
        o[dc] = __builtin_amdgcn_mfma_f32_16x16x32_bf16(pf, vf[dc][kc2], o[dc], 0, 0, 0);
    }

    // ---- QK(it+1) -> sraw (overwrite OK: all sraw reads retired at B2) ----
    if (it < 31) qk_stage();
  }

  // ---- epilogue: reduce l across the 4 quad-replicas, normalize, store ----
  l_run += __shfl_xor(l_run, 16);
  l_run += __shfl_xor(l_run, 32);
  if (quad == 0) lbuf[n16 * 17 + g] = l_run;   // l for row (h=n16, q=g)
  __syncthreads();
  float linv[4];
#pragma unroll
  for (int r = 0; r < 4; r++) linv[r] = 1.0f / lbuf[g * 17 + quad * 4 + r];
#pragma unroll
  for (int dc = 0; dc < 4; dc++)
#pragma unroll
    for (int r = 0; r < 4; r++) {
      const float v = o[dc][r] * linv[r];
      Obuf[(size_t)(b * 2048 + q0 + quad * 4 + r) * 1024 + g * 64 + dc * 16 + n16] = f2bf(v);
    }
}

extern "C" void kernel_launch(void* const* d_in, const int* in_sizes, int n_in,
                              void* d_out, int out_size, void* d_ws, size_t ws_size,
                              hipStream_t stream) {
  const float* query = (const float*)d_in[0];
  const float* key   = (const float*)d_in[1];
  const float* value = (const float*)d_in[2];
  const float* Wq = (const float*)d_in[3];
  const float* bq = (const float*)d_in[4];
  const float* Wk = (const float*)d_in[5];
  const float* bk = (const float*)d_in[6];
  const float* Wv = (const float*)d_in[7];
  const float* bv = (const float*)d_in[8];
  const float* Wc = (const float*)d_in[9];
  // d_in[10] = bc: constant along softmax axis -> provably no effect on output
  const float* Wo = (const float*)d_in[11];
  const float* bo = (const float*)d_in[12];

  char* ws = (char*)d_ws;
  const size_t MB = 1024 * 1024;
  unsigned short* q_bf  = (unsigned short*)(ws);            // 8MB; later reused as Obuf
  unsigned short* k_bf  = (unsigned short*)(ws + 8 * MB);   // 8MB; later reused as VT
  unsigned short* v_bf  = (unsigned short*)(ws + 16 * MB);  // 8MB
  unsigned short* wq_bf = (unsigned short*)(ws + 24 * MB);  // 2MB
  unsigned short* wk_bf = (unsigned short*)(ws + 26 * MB);  // 2MB
  unsigned short* wv_bf = (unsigned short*)(ws + 28 * MB);  // 2MB
  unsigned short* wo_bf = (unsigned short*)(ws + 30 * MB);  // 2MB
  unsigned short* Qb    = (unsigned short*)(ws + 32 * MB);  // 8MB
  unsigned short* Kb    = (unsigned short*)(ws + 40 * MB);  // 8MB
  unsigned short* Vb    = (unsigned short*)(ws + 48 * MB);  // 8MB  (total 56MB)
  unsigned short* VT   = k_bf;   // k_bf dead after K-projection
  unsigned short* Obuf = q_bf;   // q_bf dead after Q-projection

  ConvArgs ca;
  ca.src[0] = query; ca.dst[0] = q_bf;  ca.n[0] = 2 * 2048 * 1024;
  ca.src[1] = key;   ca.dst[1] = k_bf;  ca.n[1] = 2 * 2048 * 1024;
  ca.src[2] = value; ca.dst[2] = v_bf;  ca.n[2] = 2 * 2048 * 1024;
  ca.src[3] = Wq;    ca.dst[3] = wq_bf; ca.n[3] = 1024 * 1024;
  ca.src[4] = Wk;    ca.dst[4] = wk_bf; ca.n[4] = 1024 * 1024;
  ca.src[5] = Wv;    ca.dst[5] = wv_bf; ca.n[5] = 1024 * 1024;
  ca.src[6] = Wo;    ca.dst[6] = wo_bf; ca.n[6] = 1024 * 1024;
  convert_f32_bf16<<<dim3(2048, 7), 256, 0, stream>>>(ca);

  GemmArgs g3;
  g3.A[0] = q_bf; g3.Bt[0] = wq_bf; g3.bias[0] = bq; g3.C[0] = Qb; g3.f32out[0] = 0;
  g3.A[1] = k_bf; g3.Bt[1] = wk_bf; g3.bias[1] = bk; g3.C[1] = Kb; g3.f32out[1] = 0;
  g3.A[2] = v_bf; g3.Bt[2] = wv_bf; g3.bias[2] = bv; g3.C[2] = Vb; g3.f32out[2] = 0;
  gemm_bt<<<dim3(32, 8, 3), 256, 0, stream>>>(g3, 4096, 1024, 1024);

  transpose_v<<<dim3(32, 16, 2), 256, 0, stream>>>(Vb, VT);

  attention_fused<<<dim3(256), 1024, 0, stream>>>(Qb, Kb, VT, Wc, Obuf);

  GemmArgs g1;
  g1.A[0] = Obuf; g1.Bt[0] = wo_bf; g1.bias[0] = bo; g1.C[0] = d_out; g1.f32out[0] = 1;
  g1.A[1] = g1.A[0]; g1.Bt[1] = g1.Bt[0]; g1.bias[1] = g1.bias[0]; g1.C[1] = g1.C[0]; g1.f32out[1] = 1;
  g1.A[2] = g1.A[0]; g1.Bt[2] = g1.Bt[0]; g1.bias[2] = g1.bias[0]; g1.C[2] = g1.C[0]; g1.f32out[2] = 1;
  gemm_bt<<<dim3(32, 8, 1), 256, 0, stream>>>(g1, 4096, 1024, 1024);
}

// Round 13
// 436.478 us; speedup vs baseline: 1.1578x; 1.0030x over previous
//
#include <hip/hip_runtime.h>

// Problem constants: B=2, S=2048, E=1024, H=16, DH=64. All fp32 in/out.
// Pipeline:
//   1) convert q,k,v,Wq,Wk,Wv,Wo fp32->bf16              (1 launch)
//   2) Q/K/V projections, fused bf16 NT-GEMM (z=3 grid)  (1 launch)
//   3) V^T reshape [b][h][d][s] for PV B-fragments       (1 launch)
//   4) fused attention with cross-head logit mixing      (1 launch)
//      S'_g = sum_h M~[g,h] * (Q_h K_h^T), M~ = (I+Wc)*(log2e/8); bc dropped.
//      No max-tracking (bounded logits, exact by shift-invariance).
//      v13 = v9 attention verbatim (244us -- the 13-variant floor: time
//      tracks per-wave work x ~10 latency multiplier, invariant to barrier/
//      buffer/occupancy/scheduling changes; v12's Tk=64 falsified the last
//      structural lever). Optimization moves to the GEMMs:
//      gemm_bt upgraded to the m97 structure -- global_load_lds width-16
//      direct-to-LDS staging (m93->m97: 517->874 TF, compiler never emits
//      it on its own) + 2-barrier K-step. Staging layout already satisfies
//      the wave-uniform-base + lane*16 LDS constraint (t*16B linear).
//   5) out = O @ Wo^T + bo, fp32 to d_out                (1 launch)
// Workspace layout (56 MB total, reuse: O overlays q_bf, VT overlays k_bf).

typedef __attribute__((ext_vector_type(8))) short bf16x8_t;   // 8 bf16 (4 VGPRs)
typedef __attribute__((ext_vector_type(4))) short bf16x4_t;   // 4 bf16 (2 VGPRs)
typedef __attribute__((ext_vector_type(4))) float f32x4_t;    // MFMA accumulator

__device__ inline unsigned short f2bf(float f) {
  unsigned u = __builtin_bit_cast(unsigned, f);
  u += 0x7fffu + ((u >> 16) & 1u);          // round-to-nearest-even
  return (unsigned short)(u >> 16);
}

// Direct global->LDS async copy, 16B per lane. LDS destination must be
// wave-uniform base + lane*16 (our t*16B staging layout satisfies this).
// Completion is tracked by vmcnt; __syncthreads (vmcnt(0) drain) publishes.
#define GLDS16(gp, lp)                                                  \
  __builtin_amdgcn_global_load_lds(                                     \
      (const __attribute__((address_space(1))) unsigned int*)(gp),      \
      (__attribute__((address_space(3))) unsigned int*)(lp), 16, 0, 0)

struct ConvArgs {
  const float* src[7];
  unsigned short* dst[7];
  int n[7];
};

__global__ __launch_bounds__(256) void convert_f32_bf16(ConvArgs a) {
  const int which = blockIdx.y;
  const int i = (blockIdx.x * 256 + threadIdx.x) * 8;
  if (i >= a.n[which]) return;
  const float* s = a.src[which] + i;
  f32x4_t x0 = *(const f32x4_t*)(s);
  f32x4_t x1 = *(const f32x4_t*)(s + 4);
  bf16x8_t o;
#pragma unroll
  for (int j = 0; j < 4; j++) o[j] = (short)f2bf(x0[j]);
#pragma unroll
  for (int j = 0; j < 4; j++) o[4 + j] = (short)f2bf(x1[j]);
  *(bf16x8_t*)(a.dst[which] + i) = o;
}

// C[m][n] = sum_k A[m][k] * Bt[n][k] + bias[n].  M,N,K multiples of 128/128/32.
// 256 threads = 4 waves in 2x2; wave tile 64x64 = 4x4 frags of 16x16; BK=32.
// blockIdx.z selects one of up to 3 independent GEMMs (fused QKV launch).
// v13 (m97 structure): global_load_lds dwordx4 staging (4 per thread per
// K-step), two __syncthreads per K-step (first retires prior ds_reads,
// second drains vmcnt -> staging visible). 16KB LDS, ~3 blocks/CU when
// grid >= 768; co-resident blocks hide the barrier drain (m97: 874 TF).
struct GemmArgs {
  const unsigned short* A[3];
  const unsigned short* Bt[3];
  const float* bias[3];
  void* C[3];
  int f32out[3];
};

__global__ __launch_bounds__(256) void gemm_bt(GemmArgs ga, int M, int N, int K)
{
  __shared__ unsigned short As[128 * 32];
  __shared__ unsigned short Bs[128 * 32];
  const int z = blockIdx.z;
  const unsigned short* __restrict__ A  = ga.A[z];
  const unsigned short* __restrict__ Bt = ga.Bt[z];
  const float* __restrict__ bias = ga.bias[z];
  void* __restrict__ C = ga.C[z];
  const int f32out = ga.f32out[z];

  const int t = threadIdx.x;
  const int l = t & 63;
  const int w = t >> 6;
  const int quad = l >> 4, n16 = l & 15;
  const int wm = (w & 1) * 64, wn = (w >> 1) * 64;
  const long m0 = (long)blockIdx.x * 128, n0 = (long)blockIdx.y * 128;

  f32x4_t acc[4][4] = {};

  // staging: thread t covers tile row t>>2, cols (t&3)*8..+7; LDS dest is
  // t*16B == wave-uniform base + lane*16 (global_load_lds requirement).
  const unsigned short* gA = A + (m0 + (t >> 2)) * (long)K + (t & 3) * 8;
  const unsigned short* gB = Bt + (n0 + (t >> 2)) * (long)K + (t & 3) * 8;
  const long rowskip = 64l * K;

  for (int kt = 0; kt < K; kt += 32) {
    __syncthreads();                       // all waves done reading prior tile
    GLDS16(gA + kt, &As[t * 8]);
    GLDS16(gA + kt + rowskip, &As[2048 + t * 8]);
    GLDS16(gB + kt, &Bs[t * 8]);
    GLDS16(gB + kt + rowskip, &Bs[2048 + t * 8]);
    __syncthreads();                       // vmcnt(0) drain: staging visible

    bf16x8_t af[4], bfr[4];
#pragma unroll
    for (int i = 0; i < 4; i++) {
      af[i]  = *(const bf16x8_t*)&As[(wm + i * 16 + n16) * 32 + quad * 8];
      bfr[i] = *(const bf16x8_t*)&Bs[(wn + i * 16 + n16) * 32 + quad * 8];
    }
#pragma unroll
    for (int mi = 0; mi < 4; mi++)
#pragma unroll
      for (int ni = 0; ni < 4; ni++)
        acc[mi][ni] = __builtin_amdgcn_mfma_f32_16x16x32_bf16(af[mi], bfr[ni], acc[mi][ni], 0, 0, 0);
  }

#pragma unroll
  for (int ni = 0; ni < 4; ni++) {
    const long n = n0 + wn + ni * 16 + n16;
    const float bv = bias[n];
#pragma unroll
    for (int mi = 0; mi < 4; mi++) {
#pragma unroll
      for (int r = 0; r < 4; r++) {
        const long m = m0 + wm + mi * 16 + quad * 4 + r;  // D: row=(l>>4)*4+reg, col=l&15
        const float v = acc[mi][ni][r] + bv;
        if (f32out) ((float*)C)[m * N + n] = v;
        else ((unsigned short*)C)[m * N + n] = f2bf(v);
      }
    }
  }
}

// V [b][s][h*64+d] -> VT [b][h][d][s]
__global__ __launch_bounds__(256) void transpose_v(
    const unsigned short* __restrict__ V, unsigned short* __restrict__ VT)
{
  __shared__ unsigned short tile[64][72];   // +8 pad
  const int t = threadIdx.x;
  const int s0 = blockIdx.x * 64, h = blockIdx.y, b = blockIdx.z;
#pragma unroll
  for (int r = 0; r < 2; r++) {
    const int elem = r * 2048 + t * 8;
    const int s = elem >> 6, d = elem & 63;
    *(bf16x8_t*)&tile[s][d] =
        *(const bf16x8_t*)&V[(size_t)(b * 2048 + s0 + s) * 1024 + h * 64 + d];
  }
  __syncthreads();
#pragma unroll
  for (int r = 0; r < 2; r++) {
    const int elem = r * 2048 + t * 8;
    const int d = elem >> 6, sl = elem & 63;
    bf16x8_t o;
#pragma unroll
    for (int j = 0; j < 8; j++) o[j] = (short)tile[sl + j][d];
    *(bf16x8_t*)&VT[((size_t)(b * 16 + h) * 64 + d) * 2048 + s0 + sl] = o;
  }
}

// Fused attention (v9 verbatim -- the 244us floor of this decomposition).
// Grid 256 (1-D, XCD-decoded). 1024 threads = 16 waves, wave g: head g.
// Lane-local logits row (h=n16, q=g) via swapped mix-MFMA; p = 2^{S'}
// directly (no max; bounded logits, exact by shift-invariance).
// Double-buffered sraw/pbuf, ONE __syncthreads per k-tile:
//   iter i: PV(i-1)[pbuf parity i-1] || mix/exp/pack(i)[sraw parity i ->
//   pbuf parity i] || QK(i+1)[sraw parity i+1] -> __syncthreads.
__global__ __launch_bounds__(1024, 4) void attention_fused(
    const unsigned short* __restrict__ Qb, const unsigned short* __restrict__ Kb,
    const unsigned short* __restrict__ VT, const float* __restrict__ Wc,
    unsigned short* __restrict__ Obuf)
{
  __shared__ unsigned short sraw[2][512 * 36];  // [col=q*32+k][slot 0..31(+4)] 2x36864 B
  __shared__ unsigned short pbuf[2][16 * 580];  // [h]{q*36 + k}                2x18560 B
  __shared__ float lbuf[16 * 17];               // [h][q] stride 17             1088 B
  __shared__ unsigned short mmat[256];          // M~[g_out][h] row-major       512 B

  const int t = threadIdx.x;
  const int g = t >> 6, l = t & 63;
  const int quad = l >> 4, n16 = l & 15;

  // XCD decode: id&7 = XCD; batch pinned to an XCD half
  const int id = blockIdx.x;
  const int xcd = id & 7;
  const int b = xcd >> 2;
  const int qb = (xcd & 3) * 32 + (id >> 3);
  const int q0 = qb * 16;

  // zero both sraw buffers once: mix A-operand reads the never-written slot
  // half (h>=16 region after XOR) which must be 0, not garbage.
  for (int i = t; i < 2 * 512 * 36; i += 1024) (&sraw[0][0])[i] = 0;
  if (t < 256) {
    // M~ = (I + Wc) * (log2e / 8): exp2-domain logits
    const float v = ((((t >> 4) == (t & 15)) ? 1.0f : 0.0f) + Wc[t]) * 0.1803368801111204f;
    mmat[t] = f2bf(v);
  }
  __syncthreads();

  // mix B-frag: B[k=h=quad*8+j][n=g_out=n16]; zero for h>=16
  bf16x8_t mfrag;
  if (quad < 2) mfrag = *(const bf16x8_t*)&mmat[n16 * 16 + quad * 8];
  else { bf16x8_t z = {0, 0, 0, 0, 0, 0, 0, 0}; mfrag = z; }
  const int c7 = g >> 2;                     // col>>7 for this wave's mix chunks

  // Q A-frags: A[m=q=n16][k=d]
  bf16x8_t qf[2];
#pragma unroll
  for (int dr = 0; dr < 2; dr++)
    qf[dr] = *(const bf16x8_t*)&Qb[(size_t)(b * 2048 + q0 + n16) * 1024 + g * 64 + dr * 32 + quad * 8];

  const int slot = g ^ (quad << 3);          // sraw h-slot (writer quad == col>>7)
  const unsigned short* kptr = Kb + (size_t)(b * 2048 + n16) * 1024 + g * 64 + quad * 8;
  const unsigned short* vptr = VT + ((size_t)(b * 16 + g) * 64 + n16) * 2048 + quad * 8;

  bf16x8_t kf[2][2], vf[4];
  auto load_kf = [&](int kt) {
#pragma unroll
    for (int kc = 0; kc < 2; kc++)
#pragma unroll
      for (int dr = 0; dr < 2; dr++)
        kf[kc][dr] = *(const bf16x8_t*)(kptr + (size_t)(kt + kc * 16) * 1024 + dr * 32);
  };
  auto load_vf = [&](int kt) {
#pragma unroll
    for (int dc = 0; dc < 4; dc++)
      vf[dc] = *(const bf16x8_t*)(vptr + (size_t)dc * 16 * 2048 + kt);
  };
  auto qk_stage = [&](unsigned short* dst) {
    f32x4_t sf[2] = {};
#pragma unroll
    for (int kc = 0; kc < 2; kc++)
#pragma unroll
      for (int dr = 0; dr < 2; dr++)
        sf[kc] = __builtin_amdgcn_mfma_f32_16x16x32_bf16(qf[dr], kf[kc][dr], sf[kc], 0, 0, 0);
    // D: row=q=quad*4+r, col=key=kc*16+n16 -> dst[col=q*32+k][slot]
#pragma unroll
    for (int kc = 0; kc < 2; kc++)
#pragma unroll
      for (int r = 0; r < 4; r++)
        dst[((quad * 4 + r) * 32 + kc * 16 + n16) * 36 + slot] = f2bf(sf[kc][r]);
  };

  // prologue: QK(0) -> sraw[0]; prefetch K(1)
  load_kf(0);
  qk_stage(&sraw[0][0]);
  load_kf(32);
  __syncthreads();                            // sraw[0] visible

  f32x4_t o[4] = {};
  float l_run = 0.0f;

  for (int it = 0; it < 64; ++it) {
    const int cur = it & 1;
    const int oth = cur ^ 1;                  // parity of both (it-1) and (it+1)

    // ---- PV(it-1): accumulate (reads pbuf parity oth; no rescale) ----
    if (it > 0) {
      const unsigned short* pp = &pbuf[oth][g * 580 + n16 * 36 + quad * 8];
      bf16x4_t plo = *(const bf16x4_t*)pp;
      bf16x4_t phi = *(const bf16x4_t*)(pp + 4);
      bf16x8_t pf = {plo[0], plo[1], plo[2], plo[3], phi[0], phi[1], phi[2], phi[3]};
#pragma unroll
      for (int dc = 0; dc < 4; dc++)
        o[dc] = __builtin_amdgcn_mfma_f32_16x16x32_bf16(pf, vf[dc], o[dc], 0, 0, 0);
    }
    // ---- issue V(it) global loads (consumed by PV(it) next interval) ----
    load_vf(it * 32);

    // ---- head mix (swapped): D[key][g_out] from sraw[cur] ----
    f32x4_t mixd[2];
#pragma unroll
    for (int c2 = 0; c2 < 2; c2++) {
      const int c = g * 2 + c2;               // cols [32g+16c2, +16): q=g
      const unsigned short* sp = &sraw[cur][(c * 16 + n16) * 36 + ((quad ^ c7) << 3)];
      bf16x4_t lo = *(const bf16x4_t*)sp;     // A[m=key=n16][k=h=quad*8+j]
      bf16x4_t hi = *(const bf16x4_t*)(sp + 4);
      bf16x8_t aa = {lo[0], lo[1], lo[2], lo[3], hi[0], hi[1], hi[2], hi[3]};
      f32x4_t z = {};
      mixd[c2] = __builtin_amdgcn_mfma_f32_16x16x32_bf16(aa, mfrag, z, 0, 0, 0);
    }
    // lane holds S'[h=n16][q=g][key = c2*16 + quad*4 + r] (log2 domain)

    // ---- p = 2^{S'} directly (bounded logits; no max subtraction) ----
    float p[2][4];
    float lsum = 0.0f;
#pragma unroll
    for (int c2 = 0; c2 < 2; c2++)
#pragma unroll
      for (int r = 0; r < 4; r++) {
        p[c2][r] = exp2f(mixd[c2][r]);
        lsum += p[c2][r];
      }
    l_run += lsum;                            // lane-partial l; reduced at end

    // ---- pack P pairs in-register, write pbuf[cur] ----
    const int pbase = n16 * 580 + g * 36 + quad * 4;
#pragma unroll
    for (int c2 = 0; c2 < 2; c2++)
#pragma unroll
      for (int rp = 0; rp < 2; rp++) {
        unsigned pk;
        asm("v_cvt_pk_bf16_f32 %0, %1, %2"
            : "=v"(pk) : "v"(p[c2][2 * rp]), "v"(p[c2][2 * rp + 1]));
        *(unsigned*)&pbuf[cur][pbase + c2 * 16 + 2 * rp] = pk;
      }

    // ---- QK(it+1) -> sraw[oth]; prefetch K(it+2) ----
    if (it < 63) qk_stage(&sraw[oth][0]);
    if (it < 62) load_kf((it + 2) * 32);

    __syncthreads();  // publishes pbuf[cur], sraw[oth]; retires all LDS reads
  }

  // ---- epilogue: PV(63) (parity 1), l-reduce, normalize, store ----
  {
    const unsigned short* pp = &pbuf[1][g * 580 + n16 * 36 + quad * 8];
    bf16x4_t plo = *(const bf16x4_t*)pp;
    bf16x4_t phi = *(const bf16x4_t*)(pp + 4);
    bf16x8_t pf = {plo[0], plo[1], plo[2], plo[3], phi[0], phi[1], phi[2], phi[3]};
#pragma unroll
    for (int dc = 0; dc < 4; dc++)
      o[dc] = __builtin_amdgcn_mfma_f32_16x16x32_bf16(pf, vf[dc], o[dc], 0, 0, 0);
  }

  l_run += __shfl_xor(l_run, 16);
  l_run += __shfl_xor(l_run, 32);
  if (quad == 0) lbuf[n16 * 17 + g] = l_run;   // l for row (h=n16, q=g)
  __syncthreads();
  float linv[4];
#pragma unroll
  for (int r = 0; r < 4; r++) linv[r] = 1.0f / lbuf[g * 17 + quad * 4 + r];
#pragma unroll
  for (int dc = 0; dc < 4; dc++)
#pragma unroll
    for (int r = 0; r < 4; r++) {
      const float v = o[dc][r] * linv[r];
      Obuf[(size_t)(b * 2048 + q0 + quad * 4 + r) * 1024 + g * 64 + dc * 16 + n16] = f2bf(v);
    }
}

extern "C" void kernel_launch(void* const* d_in, const int* in_sizes, int n_in,
                              void* d_out, int out_size, void* d_ws, size_t ws_size,
                              hipStream_t stream) {
  const float* query = (const float*)d_in[0];
  const float* key   = (const float*)d_in[1];
  const float* value = (const float*)d_in[2];
  const float* Wq = (const float*)d_in[3];
  const float* bq = (const float*)d_in[4];
  const float* Wk = (const float*)d_in[5];
  const float* bk = (const float*)d_in[6];
  const float* Wv = (const float*)d_in[7];
  const float* bv = (const float*)d_in[8];
  const float* Wc = (const float*)d_in[9];
  // d_in[10] = bc: constant along softmax axis -> provably no effect on output
  const float* Wo = (const float*)d_in[11];
  const float* bo = (const float*)d_in[12];

  char* ws = (char*)d_ws;
  const size_t MB = 1024 * 1024;
  unsigned short* q_bf  = (unsigned short*)(ws);            // 8MB; later reused as Obuf
  unsigned short* k_bf  = (unsigned short*)(ws + 8 * MB);   // 8MB; later reused as VT
  unsigned short* v_bf  = (unsigned short*)(ws + 16 * MB);  // 8MB
  unsigned short* wq_bf = (unsigned short*)(ws + 24 * MB);  // 2MB
  unsigned short* wk_bf = (unsigned short*)(ws + 26 * MB);  // 2MB
  unsigned short* wv_bf = (unsigned short*)(ws + 28 * MB);  // 2MB
  unsigned short* wo_bf = (unsigned short*)(ws + 30 * MB);  // 2MB
  unsigned short* Qb    = (unsigned short*)(ws + 32 * MB);  // 8MB
  unsigned short* Kb    = (unsigned short*)(ws + 40 * MB);  // 8MB
  unsigned short* Vb    = (unsigned short*)(ws + 48 * MB);  // 8MB  (total 56MB)
  unsigned short* VT   = k_bf;   // k_bf dead after K-projection
  unsigned short* Obuf = q_bf;   // q_bf dead after Q-projection

  ConvArgs ca;
  ca.src[0] = query; ca.dst[0] = q_bf;  ca.n[0] = 2 * 2048 * 1024;
  ca.src[1] = key;   ca.dst[1] = k_bf;  ca.n[1] = 2 * 2048 * 1024;
  ca.src[2] = value; ca.dst[2] = v_bf;  ca.n[2] = 2 * 2048 * 1024;
  ca.src[3] = Wq;    ca.dst[3] = wq_bf; ca.n[3] = 1024 * 1024;
  ca.src[4] = Wk;    ca.dst[4] = wk_bf; ca.n[4] = 1024 * 1024;
  ca.src[5] = Wv;    ca.dst[5] = wv_bf; ca.n[5] = 1024 * 1024;
  ca.src[6] = Wo;    ca.dst[6] = wo_bf; ca.n[6] = 1024 * 1024;
  convert_f32_bf16<<<dim3(2048, 7), 256, 0, stream>>>(ca);

  GemmArgs g3;
  g3.A[0] = q_bf; g3.Bt[0] = wq_bf; g3.bias[0] = bq; g3.C[0] = Qb; g3.f32out[0] = 0;
  g3.A[1] = k_bf; g3.Bt[1] = wk_bf; g3.bias[1] = bk; g3.C[1] = Kb; g3.f32out[1] = 0;
  g3.A[2] = v_bf; g3.Bt[2] = wv_bf; g3.bias[2] = bv; g3.C[2] = Vb; g3.f32out[2] = 0;
  gemm_bt<<<dim3(32, 8, 3), 256, 0, stream>>>(g3, 4096, 1024, 1024);

  transpose_v<<<dim3(32, 16, 2), 256, 0, stream>>>(Vb, VT);

  attention_fused<<<dim3(256), 1024, 0, stream>>>(Qb, Kb, VT, Wc, Obuf);

  GemmArgs g1;
  g1.A[0] = Obuf; g1.Bt[0] = wo_bf; g1.bias[0] = bo; g1.C[0] = d_out; g1.f32out[0] = 1;
  g1.A[1] = g1.A[0]; g1.Bt[1] = g1.Bt[0]; g1.bias[1] = g1.bias[0]; g1.C[1] = g1.C[0]; g1.f32out[1] = 1;
  g1.A[2] = g1.A[0]; g1.Bt[2] = g1.Bt[0]; g1.bias[2] = g1.bias[0]; g1.C[2] = g1.C[0]; g1.f32out[2] = 1;
  gemm_bt<<<dim3(32, 8, 1), 256, 0, stream>>>(g1, 4096, 1024, 1024);
}

// Round 14
// 422.266 us; speedup vs baseline: 1.1968x; 1.0337x over previous
//
#include <hip/hip_runtime.h>

// Problem constants: B=2, S=2048, E=1024, H=16, DH=64. All fp32 in/out.
// Pipeline:
//   1) convert q,k,v,Wq,Wk,Wv,Wo fp32->bf16              (1 launch)
//   2) Q/K/V projections, fused bf16 NT-GEMM (z=3 grid)  (1 launch)
//      V-projection (z=2) writes its output DIRECTLY in VT[b][h][d][s]
//      layout (transpose fused into epilogue: r=0..3 accumulator values are
//      4 consecutive s -> 8B packed stores). transpose_v kernel deleted.
//      VT lives in Vb's slot (NOT k_bf: k_bf is concurrently read as the
//      K-projection's input within the same fused launch).
//   3) fused attention with cross-head logit mixing      (1 launch)
//      S'_g = sum_h M~[g,h] * (Q_h K_h^T), M~ = (I+Wc)*(log2e/8); bc dropped.
//      No max-tracking (bounded logits, exact by shift-invariance).
//      v9-verbatim attention: 242-244us floor of this decomposition
//      (13 structural variants: time = per-wave work x ~10 latency factor,
//      invariant to barrier/buffer/occupancy/scheduling).
//   4) out = O @ Wo^T + bo, fp32 to d_out                (1 launch)
// gemm_bt restored to v9's register-staged asm-prefetch form (v13 showed
// m97 global_load_lds staging is ~11us slower at K=1024: two vmcnt-drain
// barriers per short K-step dominate).
// Workspace layout (56 MB total; Obuf overlays q_bf).

typedef __attribute__((ext_vector_type(8))) short bf16x8_t;   // 8 bf16 (4 VGPRs)
typedef __attribute__((ext_vector_type(4))) short bf16x4_t;   // 4 bf16 (2 VGPRs)
typedef __attribute__((ext_vector_type(4))) float f32x4_t;    // MFMA accumulator

__device__ inline unsigned short f2bf(float f) {
  unsigned u = __builtin_bit_cast(unsigned, f);
  u += 0x7fffu + ((u >> 16) & 1u);          // round-to-nearest-even
  return (unsigned short)(u >> 16);
}

// Volatile asm 16B load (gemm staging): cannot be sunk/elided.
#define GLOAD(dst, ptr) \
  asm volatile("global_load_dwordx4 %0, %1, off" : "=v"(dst) : "v"((const void*)(ptr)))
#define WAITV0() { asm volatile("s_waitcnt vmcnt(0)"); __builtin_amdgcn_sched_barrier(0); }

// Barrier publishing LDS only (no vmcnt drain).
__device__ inline void bar_lds() {
  asm volatile("s_waitcnt lgkmcnt(0)" ::: "memory");
  __builtin_amdgcn_s_barrier();
}

struct ConvArgs {
  const float* src[7];
  unsigned short* dst[7];
  int n[7];
};

__global__ __launch_bounds__(256) void convert_f32_bf16(ConvArgs a) {
  const int which = blockIdx.y;
  const int i = (blockIdx.x * 256 + threadIdx.x) * 8;
  if (i >= a.n[which]) return;
  const float* s = a.src[which] + i;
  f32x4_t x0 = *(const f32x4_t*)(s);
  f32x4_t x1 = *(const f32x4_t*)(s + 4);
  bf16x8_t o;
#pragma unroll
  for (int j = 0; j < 4; j++) o[j] = (short)f2bf(x0[j]);
#pragma unroll
  for (int j = 0; j < 4; j++) o[4 + j] = (short)f2bf(x1[j]);
  *(bf16x8_t*)(a.dst[which] + i) = o;
}

// C[m][n] = sum_k A[m][k] * Bt[n][k] + bias[n].  M,N,K multiples of 128/128/32.
// 256 threads = 4 waves in 2x2; wave tile 64x64 = 4x4 frags of 16x16; BK=32.
// blockIdx.z selects one of up to 3 independent GEMMs (fused QKV launch).
// mode: 0 = bf16 row-major C, 1 = f32 row-major C,
//       2 = bf16 transposed VT[b][h][d][s] (M=b*2048+s, N=h*64+d) output.
struct GemmArgs {
  const unsigned short* A[3];
  const unsigned short* Bt[3];
  const float* bias[3];
  void* C[3];
  int mode[3];
};

__global__ __launch_bounds__(256) void gemm_bt(GemmArgs ga, int M, int N, int K)
{
  __shared__ unsigned short As[128 * 32];
  __shared__ unsigned short Bs[128 * 32];
  const int z = blockIdx.z;
  const unsigned short* __restrict__ A  = ga.A[z];
  const unsigned short* __restrict__ Bt = ga.Bt[z];
  const float* __restrict__ bias = ga.bias[z];
  void* __restrict__ C = ga.C[z];
  const int mode = ga.mode[z];

  const int t = threadIdx.x;
  const int l = t & 63;
  const int w = t >> 6;
  const int quad = l >> 4, n16 = l & 15;
  const int wm = (w & 1) * 64, wn = (w >> 1) * 64;
  const long m0 = (long)blockIdx.x * 128, n0 = (long)blockIdx.y * 128;

  f32x4_t acc[4][4] = {};

  // staging: thread t covers tile row t/4 (+64 on round 1), cols (t%4)*8..+7
  const unsigned short* gA = A + (m0 + (t >> 2)) * (long)K + (t & 3) * 8;
  const unsigned short* gB = Bt + (n0 + (t >> 2)) * (long)K + (t & 3) * 8;
  const long rowskip = 64l * K;

  bf16x8_t ra0, ra1, rb0, rb1;
  GLOAD(ra0, gA);            GLOAD(ra1, gA + rowskip);
  GLOAD(rb0, gB);            GLOAD(rb1, gB + rowskip);
  WAITV0();                  // tile 0 arrived (no latch crossed)

  for (int kt = 0; kt < K; kt += 32) {
    bar_lds();                             // all waves done reading prior tile
    *(bf16x8_t*)&As[t * 8] = ra0;          // elem (t>>2)*32 + (t&3)*8 == t*8
    *(bf16x8_t*)&As[2048 + t * 8] = ra1;
    *(bf16x8_t*)&Bs[t * 8] = rb0;
    *(bf16x8_t*)&Bs[2048 + t * 8] = rb1;
    bar_lds();                             // staging visible
    const long ktn = (kt + 32 < K) ? kt + 32 : 0;  // clamp (tail loads unused)
    GLOAD(ra0, gA + ktn);      GLOAD(ra1, gA + ktn + rowskip);
    GLOAD(rb0, gB + ktn);      GLOAD(rb1, gB + ktn + rowskip);

    bf16x8_t af[4], bfr[4];
#pragma unroll
    for (int i = 0; i < 4; i++) {
      af[i]  = *(const bf16x8_t*)&As[(wm + i * 16 + n16) * 32 + quad * 8];
      bfr[i] = *(const bf16x8_t*)&Bs[(wn + i * 16 + n16) * 32 + quad * 8];
    }
#pragma unroll
    for (int mi = 0; mi < 4; mi++)
#pragma unroll
      for (int ni = 0; ni < 4; ni++)
        acc[mi][ni] = __builtin_amdgcn_mfma_f32_16x16x32_bf16(af[mi], bfr[ni], acc[mi][ni], 0, 0, 0);
    WAITV0();   // next tile arrived; nothing outstanding crosses the latch
  }

  if (mode == 2) {
    // Transposed epilogue: write VT[b][h][d][s], b=m>>11, s=m&2047,
    // h=n>>6, d=n&63. r=0..3 are 4 consecutive s -> one 8B packed store.
    // A 128-row m-tile never straddles a 2048 boundary (2048 % 128 == 0).
#pragma unroll
    for (int ni = 0; ni < 4; ni++) {
      const long n = n0 + wn + ni * 16 + n16;
      const float bv = bias[n];
      const int h = (int)(n >> 6), d = (int)(n & 63);
#pragma unroll
      for (int mi = 0; mi < 4; mi++) {
        const long m = m0 + wm + mi * 16 + quad * 4;   // base of 4 consecutive rows
        const int bb = (int)(m >> 11), s = (int)(m & 2047);
        bf16x4_t o4;
#pragma unroll
        for (int r = 0; r < 4; r++) o4[r] = (short)f2bf(acc[mi][ni][r] + bv);
        *(bf16x4_t*)&((unsigned short*)C)[((size_t)(bb * 16 + h) * 64 + d) * 2048 + s] = o4;
      }
    }
  } else {
#pragma unroll
    for (int ni = 0; ni < 4; ni++) {
      const long n = n0 + wn + ni * 16 + n16;
      const float bv = bias[n];
#pragma unroll
      for (int mi = 0; mi < 4; mi++) {
#pragma unroll
        for (int r = 0; r < 4; r++) {
          const long m = m0 + wm + mi * 16 + quad * 4 + r;  // D: row=(l>>4)*4+reg, col=l&15
          const float v = acc[mi][ni][r] + bv;
          if (mode == 1) ((float*)C)[m * N + n] = v;
          else ((unsigned short*)C)[m * N + n] = f2bf(v);
        }
      }
    }
  }
}

// Fused attention (v9 verbatim -- the 242-244us floor of this decomposition).
// Grid 256 (1-D, XCD-decoded). 1024 threads = 16 waves, wave g: head g.
// Lane-local logits row (h=n16, q=g) via swapped mix-MFMA; p = 2^{S'}
// directly (no max; bounded logits, exact by shift-invariance).
// Double-buffered sraw/pbuf, ONE __syncthreads per k-tile:
//   iter i: PV(i-1)[pbuf parity i-1] || mix/exp/pack(i)[sraw parity i ->
//   pbuf parity i] || QK(i+1)[sraw parity i+1] -> __syncthreads.
__global__ __launch_bounds__(1024, 4) void attention_fused(
    const unsigned short* __restrict__ Qb, const unsigned short* __restrict__ Kb,
    const unsigned short* __restrict__ VT, const float* __restrict__ Wc,
    unsigned short* __restrict__ Obuf)
{
  __shared__ unsigned short sraw[2][512 * 36];  // [col=q*32+k][slot 0..31(+4)] 2x36864 B
  __shared__ unsigned short pbuf[2][16 * 580];  // [h]{q*36 + k}                2x18560 B
  __shared__ float lbuf[16 * 17];               // [h][q] stride 17             1088 B
  __shared__ unsigned short mmat[256];          // M~[g_out][h] row-major       512 B

  const int t = threadIdx.x;
  const int g = t >> 6, l = t & 63;
  const int quad = l >> 4, n16 = l & 15;

  // XCD decode: id&7 = XCD; batch pinned to an XCD half
  const int id = blockIdx.x;
  const int xcd = id & 7;
  const int b = xcd >> 2;
  const int qb = (xcd & 3) * 32 + (id >> 3);
  const int q0 = qb * 16;

  // zero both sraw buffers once: mix A-operand reads the never-written slot
  // half (h>=16 region after XOR) which must be 0, not garbage.
  for (int i = t; i < 2 * 512 * 36; i += 1024) (&sraw[0][0])[i] = 0;
  if (t < 256) {
    // M~ = (I + Wc) * (log2e / 8): exp2-domain logits
    const float v = ((((t >> 4) == (t & 15)) ? 1.0f : 0.0f) + Wc[t]) * 0.1803368801111204f;
    mmat[t] = f2bf(v);
  }
  __syncthreads();

  // mix B-frag: B[k=h=quad*8+j][n=g_out=n16]; zero for h>=16
  bf16x8_t mfrag;
  if (quad < 2) mfrag = *(const bf16x8_t*)&mmat[n16 * 16 + quad * 8];
  else { bf16x8_t z = {0, 0, 0, 0, 0, 0, 0, 0}; mfrag = z; }
  const int c7 = g >> 2;                     // col>>7 for this wave's mix chunks

  // Q A-frags: A[m=q=n16][k=d]
  bf16x8_t qf[2];
#pragma unroll
  for (int dr = 0; dr < 2; dr++)
    qf[dr] = *(const bf16x8_t*)&Qb[(size_t)(b * 2048 + q0 + n16) * 1024 + g * 64 + dr * 32 + quad * 8];

  const int slot = g ^ (quad << 3);          // sraw h-slot (writer quad == col>>7)
  const unsigned short* kptr = Kb + (size_t)(b * 2048 + n16) * 1024 + g * 64 + quad * 8;
  const unsigned short* vptr = VT + ((size_t)(b * 16 + g) * 64 + n16) * 2048 + quad * 8;

  bf16x8_t kf[2][2], vf[4];
  auto load_kf = [&](int kt) {
#pragma unroll
    for (int kc = 0; kc < 2; kc++)
#pragma unroll
      for (int dr = 0; dr < 2; dr++)
        kf[kc][dr] = *(const bf16x8_t*)(kptr + (size_t)(kt + kc * 16) * 1024 + dr * 32);
  };
  auto load_vf = [&](int kt) {
#pragma unroll
    for (int dc = 0; dc < 4; dc++)
      vf[dc] = *(const bf16x8_t*)(vptr + (size_t)dc * 16 * 2048 + kt);
  };
  auto qk_stage = [&](unsigned short* dst) {
    f32x4_t sf[2] = {};
#pragma unroll
    for (int kc = 0; kc < 2; kc++)
#pragma unroll
      for (int dr = 0; dr < 2; dr++)
        sf[kc] = __builtin_amdgcn_mfma_f32_16x16x32_bf16(qf[dr], kf[kc][dr], sf[kc], 0, 0, 0);
    // D: row=q=quad*4+r, col=key=kc*16+n16 -> dst[col=q*32+k][slot]
#pragma unroll
    for (int kc = 0; kc < 2; kc++)
#pragma unroll
      for (int r = 0; r < 4; r++)
        dst[((quad * 4 + r) * 32 + kc * 16 + n16) * 36 + slot] = f2bf(sf[kc][r]);
  };

  // prologue: QK(0) -> sraw[0]; prefetch K(1)
  load_kf(0);
  qk_stage(&sraw[0][0]);
  load_kf(32);
  __syncthreads();                            // sraw[0] visible

  f32x4_t o[4] = {};
  float l_run = 0.0f;

  for (int it = 0; it < 64; ++it) {
    const int cur = it & 1;
    const int oth = cur ^ 1;                  // parity of both (it-1) and (it+1)

    // ---- PV(it-1): accumulate (reads pbuf parity oth; no rescale) ----
    if (it > 0) {
      const unsigned short* pp = &pbuf[oth][g * 580 + n16 * 36 + quad * 8];
      bf16x4_t plo = *(const bf16x4_t*)pp;
      bf16x4_t phi = *(const bf16x4_t*)(pp + 4);
      bf16x8_t pf = {plo[0], plo[1], plo[2], plo[3], phi[0], phi[1], phi[2], phi[3]};
#pragma unroll
      for (int dc = 0; dc < 4; dc++)
        o[dc] = __builtin_amdgcn_mfma_f32_16x16x32_bf16(pf, vf[dc], o[dc], 0, 0, 0);
    }
    // ---- issue V(it) global loads (consumed by PV(it) next interval) ----
    load_vf(it * 32);

    // ---- head mix (swapped): D[key][g_out] from sraw[cur] ----
    f32x4_t mixd[2];
#pragma unroll
    for (int c2 = 0; c2 < 2; c2++) {
      const int c = g * 2 + c2;               // cols [32g+16c2, +16): q=g
      const unsigned short* sp = &sraw[cur][(c * 16 + n16) * 36 + ((quad ^ c7) << 3)];
      bf16x4_t lo = *(const bf16x4_t*)sp;     // A[m=key=n16][k=h=quad*8+j]
      bf16x4_t hi = *(const bf16x4_t*)(sp + 4);
      bf16x8_t aa = {lo[0], lo[1], lo[2], lo[3], hi[0], hi[1], hi[2], hi[3]};
      f32x4_t z = {};
      mixd[c2] = __builtin_amdgcn_mfma_f32_16x16x32_bf16(aa, mfrag, z, 0, 0, 0);
    }
    // lane holds S'[h=n16][q=g][key = c2*16 + quad*4 + r] (log2 domain)

    // ---- p = 2^{S'} directly (bounded logits; no max subtraction) ----
    float p[2][4];
    float lsum = 0.0f;
#pragma unroll
    for (int c2 = 0; c2 < 2; c2++)
#pragma unroll
      for (int r = 0; r < 4; r++) {
        p[c2][r] = exp2f(mixd[c2][r]);
        lsum += p[c2][r];
      }
    l_run += lsum;                            // lane-partial l; reduced at end

    // ---- pack P pairs in-register, write pbuf[cur] ----
    const int pbase = n16 * 580 + g * 36 + quad * 4;
#pragma unroll
    for (int c2 = 0; c2 < 2; c2++)
#pragma unroll
      for (int rp = 0; rp < 2; rp++) {
        unsigned pk;
        asm("v_cvt_pk_bf16_f32 %0, %1, %2"
            : "=v"(pk) : "v"(p[c2][2 * rp]), "v"(p[c2][2 * rp + 1]));
        *(unsigned*)&pbuf[cur][pbase + c2 * 16 + 2 * rp] = pk;
      }

    // ---- QK(it+1) -> sraw[oth]; prefetch K(it+2) ----
    if (it < 63) qk_stage(&sraw[oth][0]);
    if (it < 62) load_kf((it + 2) * 32);

    __syncthreads();  // publishes pbuf[cur], sraw[oth]; retires all LDS reads
  }

  // ---- epilogue: PV(63) (parity 1), l-reduce, normalize, store ----
  {
    const unsigned short* pp = &pbuf[1][g * 580 + n16 * 36 + quad * 8];
    bf16x4_t plo = *(const bf16x4_t*)pp;
    bf16x4_t phi = *(const bf16x4_t*)(pp + 4);
    bf16x8_t pf = {plo[0], plo[1], plo[2], plo[3], phi[0], phi[1], phi[2], phi[3]};
#pragma unroll
    for (int dc = 0; dc < 4; dc++)
      o[dc] = __builtin_amdgcn_mfma_f32_16x16x32_bf16(pf, vf[dc], o[dc], 0, 0, 0);
  }

  l_run += __shfl_xor(l_run, 16);
  l_run += __shfl_xor(l_run, 32);
  if (quad == 0) lbuf[n16 * 17 + g] = l_run;   // l for row (h=n16, q=g)
  __syncthreads();
  float linv[4];
#pragma unroll
  for (int r = 0; r < 4; r++) linv[r] = 1.0f / lbuf[g * 17 + quad * 4 + r];
#pragma unroll
  for (int dc = 0; dc < 4; dc++)
#pragma unroll
    for (int r = 0; r < 4; r++) {
      const float v = o[dc][r] * linv[r];
      Obuf[(size_t)(b * 2048 + q0 + quad * 4 + r) * 1024 + g * 64 + dc * 16 + n16] = f2bf(v);
    }
}

extern "C" void kernel_launch(void* const* d_in, const int* in_sizes, int n_in,
                              void* d_out, int out_size, void* d_ws, size_t ws_size,
                              hipStream_t stream) {
  const float* query = (const float*)d_in[0];
  const float* key   = (const float*)d_in[1];
  const float* value = (const float*)d_in[2];
  const float* Wq = (const float*)d_in[3];
  const float* bq = (const float*)d_in[4];
  const float* Wk = (const float*)d_in[5];
  const float* bk = (const float*)d_in[6];
  const float* Wv = (const float*)d_in[7];
  const float* bv = (const float*)d_in[8];
  const float* Wc = (const float*)d_in[9];
  // d_in[10] = bc: constant along softmax axis -> provably no effect on output
  const float* Wo = (const float*)d_in[11];
  const float* bo = (const float*)d_in[12];

  char* ws = (char*)d_ws;
  const size_t MB = 1024 * 1024;
  unsigned short* q_bf  = (unsigned short*)(ws);            // 8MB; later reused as Obuf
  unsigned short* k_bf  = (unsigned short*)(ws + 8 * MB);   // 8MB
  unsigned short* v_bf  = (unsigned short*)(ws + 16 * MB);  // 8MB
  unsigned short* wq_bf = (unsigned short*)(ws + 24 * MB);  // 2MB
  unsigned short* wk_bf = (unsigned short*)(ws + 26 * MB);  // 2MB
  unsigned short* wv_bf = (unsigned short*)(ws + 28 * MB);  // 2MB
  unsigned short* wo_bf = (unsigned short*)(ws + 30 * MB);  // 2MB
  unsigned short* Qb    = (unsigned short*)(ws + 32 * MB);  // 8MB
  unsigned short* Kb    = (unsigned short*)(ws + 40 * MB);  // 8MB
  unsigned short* VT    = (unsigned short*)(ws + 48 * MB);  // 8MB (V-proj writes VT directly)
  unsigned short* Obuf = q_bf;   // q_bf dead after Q-projection

  ConvArgs ca;
  ca.src[0] = query; ca.dst[0] = q_bf;  ca.n[0] = 2 * 2048 * 1024;
  ca.src[1] = key;   ca.dst[1] = k_bf;  ca.n[1] = 2 * 2048 * 1024;
  ca.src[2] = value; ca.dst[2] = v_bf;  ca.n[2] = 2 * 2048 * 1024;
  ca.src[3] = Wq;    ca.dst[3] = wq_bf; ca.n[3] = 1024 * 1024;
  ca.src[4] = Wk;    ca.dst[4] = wk_bf; ca.n[4] = 1024 * 1024;
  ca.src[5] = Wv;    ca.dst[5] = wv_bf; ca.n[5] = 1024 * 1024;
  ca.src[6] = Wo;    ca.dst[6] = wo_bf; ca.n[6] = 1024 * 1024;
  convert_f32_bf16<<<dim3(2048, 7), 256, 0, stream>>>(ca);

  GemmArgs g3;
  g3.A[0] = q_bf; g3.Bt[0] = wq_bf; g3.bias[0] = bq; g3.C[0] = Qb; g3.mode[0] = 0;
  g3.A[1] = k_bf; g3.Bt[1] = wk_bf; g3.bias[1] = bk; g3.C[1] = Kb; g3.mode[1] = 0;
  g3.A[2] = v_bf; g3.Bt[2] = wv_bf; g3.bias[2] = bv; g3.C[2] = VT; g3.mode[2] = 2;
  gemm_bt<<<dim3(32, 8, 3), 256, 0, stream>>>(g3, 4096, 1024, 1024);

  attention_fused<<<dim3(256), 1024, 0, stream>>>(Qb, Kb, VT, Wc, Obuf);

  GemmArgs g1;
  g1.A[0] = Obuf; g1.Bt[0] = wo_bf; g1.bias[0] = bo; g1.C[0] = d_out; g1.mode[0] = 1;
  g1.A[1] = g1.A[0]; g1.Bt[1] = g1.Bt[0]; g1.bias[1] = g1.bias[0]; g1.C[1] = g1.C[0]; g1.mode[1] = 1;
  g1.A[2] = g1.A[0]; g1.Bt[2] = g1.Bt[0]; g1.bias[2] = g1.bias[0]; g1.C[2] = g1.C[0]; g1.mode[2] = 1;
  gemm_bt<<<dim3(32, 8, 1), 256, 0, stream>>>(g1, 4096, 1024, 1024);
}